// Round 10
// baseline (117.512 us; speedup 1.0000x reference)
//
#include <hip/hip_runtime.h>
#include <math.h>

typedef float f32x16 __attribute__((ext_vector_type(16)));
typedef short short8 __attribute__((ext_vector_type(8)));

__device__ __forceinline__ short bf16r(float f) {
    union { float f; unsigned u; } x; x.f = f;
    unsigned u = x.u + 0x7fffu + ((x.u >> 16) & 1u);
    return (short)(u >> 16);
}

// ---------------------------------------------------------------------------
// pack_kernel: repack w2 (co,ci,j) fp32 -> 32x32x16 B-fragment-ordered bf16.
// B-frag (k=16, n=32): lane holds B[k = 8*(lane>>5)+i][n = lane&31].
// wpack[(((c*K + j)*4 + kb)*64 + lane)*8 + i]
//   = w2[co = c*32+(lane&31)][ci = kb*16 + 8*(lane>>5) + i][j]
// ---------------------------------------------------------------------------
template<int K>
__device__ __forceinline__ void pack_branch(const float* __restrict__ w2,
                                            short* __restrict__ wpack, int u) {
    int lane = u & 63;
    int kb   = (u >> 6) & 3;
    int rem  = u >> 8;          // c*K + j
    int j = rem % K, c = rem / K;
    int co  = c * 32 + (lane & 31);
    int cib = kb * 16 + 8 * (lane >> 5);
    short8 v;
    #pragma unroll
    for (int i = 0; i < 8; ++i)
        v[i] = bf16r(w2[(co * 64 + (cib + i)) * K + j]);
    *reinterpret_cast<short8*>(wpack + (size_t)u * 8) = v;
}

__global__ __launch_bounds__(256) void pack_kernel(
    const float* __restrict__ w23, const float* __restrict__ w25,
    const float* __restrict__ w27,
    short* __restrict__ wp3, short* __restrict__ wp5, short* __restrict__ wp7)
{
    int tid = blockIdx.x * 256 + threadIdx.x;
    const int n3 = 1024 * 3;   // 3072
    const int n5 = 1024 * 5;   // 5120
    const int n7 = 1024 * 7;   // 7168
    if (tid < n3)                pack_branch<3>(w23, wp3, tid);
    else if (tid < n3 + n5)      pack_branch<5>(w25, wp5, tid - n3);
    else if (tid < n3 + n5 + n7) pack_branch<7>(w27, wp7, tid - n3 - n5);
}

// ---------------------------------------------------------------------------
// mfma_pass<K,LT0,NLT>: one lt-pass. B register double-buffered; A from
// swizzled LDS with lt as immediate offsets (swizzle lt-invariant: 32%8==0).
// ---------------------------------------------------------------------------
template<int K, int LT0, int NLT>
__device__ __forceinline__ void mfma_pass(
    const short* t1s, const short8* wpB, int lane, f32x16* acc)
{
    constexpr int PAD = (K - 1) / 2;
    const int r0 = (lane & 31) + 3 - PAD;
    const int cb = 8 * (lane >> 5);
    short8 bcur = wpB[0];
    #pragma unroll
    for (int m = 0; m < 4 * K; ++m) {
        const short8 bnxt = (m + 1 < 4 * K) ? wpB[(m + 1) * 64] : bcur;
        const int j  = m >> 2, kb = m & 3;
        const int r  = r0 + j;
        const int col = (kb * 16 + cb) ^ ((r & 7) << 3);
        const short* ab = &t1s[r * 64 + col];
        #pragma unroll
        for (int lt = 0; lt < NLT; ++lt)
            acc[lt] = __builtin_amdgcn_mfma_f32_32x32x16_bf16(
                *reinterpret_cast<const short8*>(ab + (LT0 + lt) * 2048),
                bcur, acc[lt], 0, 0, 0);
        bcur = bnxt;
    }
}

// pool32<H,LT0,NLT>: C/D 32x32: row = (reg&3)+8*(reg>>2)+4*H, col = lane&31.
template<int H, int LT0, int NLT>
__device__ __forceinline__ void pool32(const f32x16* acc, float bb, float* pb) {
    #pragma unroll
    for (int lt = 0; lt < NLT; ++lt) {
        #pragma unroll
        for (int reg = 0; reg < 16; ++reg) {
            const int l = (LT0 + lt) * 32 + (reg & 3) + 8 * (reg >> 2) + 4 * H;
            if (l < 200)
                pb[l / 20] += fmaxf(acc[lt][reg] + bb, 0.0f);
        }
    }
}

// ---------------------------------------------------------------------------
// branch_body<K>: one (bn,branch), 256 threads / 4 waves, wave w owns c = w
// (co block of 32). conv1 -> t1s bf16 swizzled; conv2 = 32x32x16 MFMA in two
// lt-passes (acc <= 64 VGPR); register pooling + shfl(32) -> pooled_s;
// coalesced xfc partial -> xfeatP[br][bn][32].
// ---------------------------------------------------------------------------
template<int K>
__device__ __forceinline__ void branch_body(
    const int bn, const int t,
    const float* __restrict__ x,
    const float* __restrict__ w1, const float* __restrict__ b1,
    const float* __restrict__ b2, const short* __restrict__ wpack,
    const float* __restrict__ w_xfc_br, float* __restrict__ xfeatP_br,
    float* xs, short* t1s, float* pooled_s, float* b2s)
{
    constexpr int PAD = (K - 1) / 2;
    const int lane = t & 63;
    const int w    = t >> 6;            // 0..3 = c
    const int h    = lane >> 5;

    // ---- P0: zero halos, preload b2 ----
    if (t < 208) xs[t] = 0.0f;
    for (int idx = t; idx < 32 * 64; idx += 256) {  // halo rows 0..2, 203..231
        int rr = idx >> 6;
        int row = (rr < 3) ? rr : (200 + rr);
        t1s[row * 64 + (idx & 63)] = 0;
    }
    if (t < 128) b2s[t] = b2[t];
    __syncthreads();

    if (t < 200) xs[3 + t] = x[bn * 200 + t];
    __syncthreads();

    // ---- P1: conv1 (ci = lane, l strided by wave), bf16 swizzled write ----
    {
        float w1_0 = w1[lane * K + 0], w1_1 = w1[lane * K + 1], w1_2 = w1[lane * K + 2];
        float w1_3 = 0.f, w1_4 = 0.f, w1_5 = 0.f, w1_6 = 0.f;
        if (K > 3) { w1_3 = w1[lane * K + 3]; w1_4 = w1[lane * K + 4]; }
        if (K > 5) { w1_5 = w1[lane * K + 5]; w1_6 = w1[lane * K + 6]; }
        const float b1r = b1[lane];
        for (int l = w; l < 200; l += 4) {
            const float* xp = &xs[3 + l - PAD];
            float a = b1r;
            a = fmaf(w1_0, xp[0], a);
            a = fmaf(w1_1, xp[1], a);
            a = fmaf(w1_2, xp[2], a);
            if (K > 3) { a = fmaf(w1_3, xp[3], a); a = fmaf(w1_4, xp[4], a); }
            if (K > 5) { a = fmaf(w1_5, xp[5], a); a = fmaf(w1_6, xp[6], a); }
            const int row = l + 3;
            t1s[row * 64 + (lane ^ ((row & 7) << 3))] = bf16r(fmaxf(a, 0.0f));
        }
    }
    __syncthreads();

    // ---- P2: MFMA, two lt-passes ----
    const int co = w * 32 + (lane & 31);
    const float bb = b2s[co];
    const short8* wpB = reinterpret_cast<const short8*>(wpack)
                        + (size_t)(w * K * 4) * 64 + lane;
    float pb[10];
    #pragma unroll
    for (int b = 0; b < 10; ++b) pb[b] = 0.0f;
    {
        f32x16 acc[4];
        #pragma unroll
        for (int i = 0; i < 4; ++i) acc[i] = (f32x16)(0.0f);
        mfma_pass<K, 0, 4>(t1s, wpB, lane, acc);
        if (h == 0) pool32<0, 0, 4>(acc, bb, pb);
        else        pool32<1, 0, 4>(acc, bb, pb);
    }
    {
        f32x16 acc[3];
        #pragma unroll
        for (int i = 0; i < 3; ++i) acc[i] = (f32x16)(0.0f);
        mfma_pass<K, 4, 3>(t1s, wpB, lane, acc);
        if (h == 0) pool32<0, 4, 3>(acc, bb, pb);
        else        pool32<1, 4, 3>(acc, bb, pb);
    }

    // ---- P3: reduce across the 2 co-sharing lanes, store pooled_s ----
    #pragma unroll
    for (int b = 0; b < 10; ++b) pb[b] += __shfl_xor(pb[b], 32);
    if (lane < 32) {
        #pragma unroll
        for (int b = 0; b < 10; ++b)
            pooled_s[co * 10 + b] = pb[b];
    }
    __syncthreads();

    // ---- P4: xfc partial: o = t>>3, part = t&7; coalesced f32x4 ----
    {
        typedef float f32x4v __attribute__((ext_vector_type(4)));
        const int o = t >> 3, part = t & 7;
        const f32x4v* wr4 = reinterpret_cast<const f32x4v*>(w_xfc_br + o * 3840);
        const f32x4v* pp4 = reinterpret_cast<const f32x4v*>(pooled_s);
        float s0 = 0.0f, s1 = 0.0f;
        #pragma unroll
        for (int i = 0; i < 40; ++i) {
            const f32x4v wv = wr4[part + 8 * i];
            const f32x4v pv = pp4[part + 8 * i];
            float s = wv[0] * pv[0];
            s = fmaf(wv[1], pv[1], s);
            s = fmaf(wv[2], pv[2], s);
            s = fmaf(wv[3], pv[3], s);
            if (i & 1) s1 += s; else s0 += s;
        }
        float a = s0 + s1;
        a += __shfl_xor(a, 1);
        a += __shfl_xor(a, 2);
        a += __shfl_xor(a, 4);
        if (part == 0) xfeatP_br[bn * 32 + o] = a * 0.05f;
    }
}

__global__ __launch_bounds__(256, 4) void branch_fused(
    const float* __restrict__ x, const float* __restrict__ xmask,
    const float* __restrict__ w1_3, const float* __restrict__ b1_3,
    const float* __restrict__ b2_3, const short* __restrict__ wp3,
    const float* __restrict__ w1_5, const float* __restrict__ b1_5,
    const float* __restrict__ b2_5, const short* __restrict__ wp5,
    const float* __restrict__ w1_7, const float* __restrict__ b1_7,
    const float* __restrict__ b2_7, const short* __restrict__ wp7,
    const float* __restrict__ w_xfc, float* __restrict__ xfeatP)
{
    __shared__ float xs[208];
    __shared__ short t1s[232 * 64];
    __shared__ __align__(16) float pooled_s[1280];
    __shared__ float b2s[128];

    const int bx = blockIdx.x;
    const int br = bx % 3;
    const int bn = bx / 3;
    const int t  = threadIdx.x;

    if (xmask[bn] == 0.0f) return;      // tail multiplies row by 0 -> exact

    if (br == 0)
        branch_body<3>(bn, t, x, w1_3, b1_3, b2_3, wp3,
                       w_xfc,        xfeatP,             xs, t1s, pooled_s, b2s);
    else if (br == 1)
        branch_body<5>(bn, t, x, w1_5, b1_5, b2_5, wp5,
                       w_xfc + 1280, xfeatP + 512 * 32,  xs, t1s, pooled_s, b2s);
    else
        branch_body<7>(bn, t, x, w1_7, b1_7, b2_7, wp7,
                       w_xfc + 2560, xfeatP + 1024 * 32, xs, t1s, pooled_s, b2s);
}

// ---------------------------------------------------------------------------
// Tail: elements processor + fuse + 4-head attention + pool + regressor.
// One block per batch b (32 blocks). xfeat = (sum of 3 partials + b_xfc) *
// xmask — masked rows' unwritten (finite poison) partials zeroed exactly.
// ---------------------------------------------------------------------------
__global__ __launch_bounds__(256) void tail_kernel(
    const float* __restrict__ xfeatP,     // (3, 512, 32)
    const float* __restrict__ b_xfc,      // (32,)
    const float* __restrict__ xmaskp,     // (512,)
    const float* __restrict__ elem_info,  // (32, 16, 7)
    const float* __restrict__ emaskp,     // (32, 16)
    const float* __restrict__ w_float, const float* __restrict__ b_float,
    const float* __restrict__ atom_emb, const float* __restrict__ type_emb,
    const float* __restrict__ w_fuse,  const float* __restrict__ b_fuse,
    const float* __restrict__ in_w,    const float* __restrict__ in_b,
    const float* __restrict__ out_w,   const float* __restrict__ out_b,
    const float* __restrict__ w_fc1,   const float* __restrict__ b_fc1,
    const float* __restrict__ w_fc2,   const float* __restrict__ b_fc2,
    float* __restrict__ out)              // (32,)
{
    const int b = blockIdx.x;
    const int t = threadIdx.x;

    __shared__ float fu[16][60];
    __shared__ float fused[16][64];
    __shared__ float qkvs[16][192];
    __shared__ float sc[4][16][16];
    __shared__ float ao[16][64];
    __shared__ float aoo[16][64];
    __shared__ float p2s[64];
    __shared__ float hs[64];
    __shared__ float em[16];

    if (t < 16) em[t] = emaskp[b * 16 + t];
    for (int d = t; d < 512; d += 256) {
        int n = d >> 5, o = d & 31;
        const int bn = b * 16 + n;
        float a = xfeatP[bn * 32 + o]
                + xfeatP[(512 + bn) * 32 + o]
                + xfeatP[(1024 + bn) * 32 + o];
        fu[n][o] = (a + b_xfc[o]) * xmaskp[bn];
    }
    __syncthreads();

    {
        int n = t >> 4, slot = t & 15;
        float m  = em[n];
        float vE = (m >= 0.5f) ? 1.0f : 0.0f;
        const float* ei = elem_info + (b * 16 + n) * 7;
        float a = b_float[slot];
        #pragma unroll
        for (int i = 0; i < 5; ++i)
            a = fmaf(ei[i] * m, w_float[slot * 5 + i], a);
        fu[n][32 + slot] = fmaxf(a, 0.0f) * vE * m;

        int an = (int)(ei[5] * m);
        int et = (int)(ei[6] * m);
        float take = (vE != 0.0f && an >= 1 && an <= 94) ? 1.0f : 0.0f;
        int anc = an < 0 ? 0 : (an > 94 ? 94 : an);
        int etc = et < 0 ? 0 : (et > 5 ? 5 : et);
        if (slot < 8)
            fu[n][48 + slot] = atom_emb[anc * 8 + slot] * take * m;
        else if (slot < 12)
            fu[n][56 + (slot - 8)] = type_emb[etc * 4 + (slot - 8)] * take * m;
    }
    __syncthreads();

    for (int d = t; d < 1024; d += 256) {
        int n = d >> 6, o = d & 63;
        float a = b_fuse[o];
        const float* wr = w_fuse + o * 60;
        #pragma unroll
        for (int i = 0; i < 60; ++i) a = fmaf(fu[n][i], wr[i], a);
        fused[n][o] = a * em[n];
    }
    __syncthreads();

    for (int d = t; d < 3072; d += 256) {
        int n = d / 192, rr = d - n * 192;
        float a = in_b[rr];
        const float* wr = in_w + rr * 64;
        #pragma unroll
        for (int i = 0; i < 64; ++i) a = fmaf(fused[n][i], wr[i], a);
        qkvs[n][rr] = a;
    }
    __syncthreads();

    for (int d = t; d < 1024; d += 256) {
        int h = d >> 8, i = (d >> 4) & 15, j = d & 15;
        float a = 0.0f;
        #pragma unroll
        for (int dd = 0; dd < 16; ++dd)
            a = fmaf(qkvs[i][h * 16 + dd], qkvs[j][64 + h * 16 + dd], a);
        a *= 0.25f;
        if (em[j] < 0.5f) a = -1e30f;
        sc[h][i][j] = a;
    }
    __syncthreads();

    if (t < 64) {
        int h = t >> 4, i = t & 15;
        float mx = -3.4e38f;
        #pragma unroll
        for (int j = 0; j < 16; ++j) mx = fmaxf(mx, sc[h][i][j]);
        float e[16];
        float s = 0.0f;
        #pragma unroll
        for (int j = 0; j < 16; ++j) { e[j] = expf(sc[h][i][j] - mx); s += e[j]; }
        float inv = 1.0f / s;
        #pragma unroll
        for (int j = 0; j < 16; ++j) sc[h][i][j] = e[j] * inv;
    }
    __syncthreads();

    for (int d = t; d < 1024; d += 256) {
        int n = d >> 6, e = d & 63, h = e >> 4;
        float a = 0.0f;
        #pragma unroll
        for (int j = 0; j < 16; ++j)
            a = fmaf(sc[h][n][j], qkvs[j][128 + e], a);
        ao[n][e] = a;
    }
    __syncthreads();

    for (int d = t; d < 1024; d += 256) {
        int n = d >> 6, o = d & 63;
        float a = out_b[o];
        const float* wr = out_w + o * 64;
        #pragma unroll
        for (int i = 0; i < 64; ++i) a = fmaf(ao[n][i], wr[i], a);
        aoo[n][o] = a * em[n];
    }
    __syncthreads();

    if (t < 64) {
        float s = 0.0f, ms = 0.0f;
        #pragma unroll
        for (int n = 0; n < 16; ++n) { s += aoo[n][t]; ms += em[n]; }
        p2s[t] = s / (ms + 1e-8f);
    }
    __syncthreads();

    if (t < 64) {
        float a = b_fc1[t];
        const float* wr = w_fc1 + t * 64;
        #pragma unroll
        for (int i = 0; i < 64; ++i) a = fmaf(p2s[i], wr[i], a);
        hs[t] = fmaxf(a, 0.0f);
    }
    __syncthreads();

    if (t < 64) {
        float v = hs[t] * w_fc2[t];
        #pragma unroll
        for (int d2 = 32; d2 >= 1; d2 >>= 1) v += __shfl_xor(v, d2);
        if (t == 0) out[b] = v + b_fc2[0];
    }
}

extern "C" void kernel_launch(void* const* d_in, const int* in_sizes, int n_in,
                              void* d_out, int out_size, void* d_ws, size_t ws_size,
                              hipStream_t stream)
{
    (void)in_sizes; (void)n_in; (void)out_size; (void)ws_size;
    const float* x     = (const float*)d_in[0];
    const float* xmask = (const float*)d_in[1];
    const float* einfo = (const float*)d_in[2];
    const float* emask = (const float*)d_in[3];

    float* xfeatP = (float*)d_ws;                 // 3*512*32 f32 = 196.6 KB
    short* wp3 = (short*)(xfeatP + 3 * 512 * 32); // 3072*8 shorts
    short* wp5 = wp3 + 24576;                     // 5120*8 shorts
    short* wp7 = wp5 + 40960;                     // 7168*8 shorts

    pack_kernel<<<60, 256, 0, stream>>>(
        (const float*)d_in[6], (const float*)d_in[10], (const float*)d_in[14],
        wp3, wp5, wp7);

    branch_fused<<<1536, 256, 0, stream>>>(x, xmask,
        (const float*)d_in[4],  (const float*)d_in[5],  (const float*)d_in[7],  wp3,
        (const float*)d_in[8],  (const float*)d_in[9],  (const float*)d_in[11], wp5,
        (const float*)d_in[12], (const float*)d_in[13], (const float*)d_in[15], wp7,
        (const float*)d_in[16], xfeatP);

    tail_kernel<<<32, 256, 0, stream>>>(xfeatP,
        (const float*)d_in[17], xmask, einfo, emask,
        (const float*)d_in[18], (const float*)d_in[19],
        (const float*)d_in[20], (const float*)d_in[21],
        (const float*)d_in[22], (const float*)d_in[23],
        (const float*)d_in[24], (const float*)d_in[25],
        (const float*)d_in[26], (const float*)d_in[27],
        (const float*)d_in[28], (const float*)d_in[29],
        (const float*)d_in[30], (const float*)d_in[31],
        (float*)d_out);
}

// Round 11
// 86.811 us; speedup vs baseline: 1.3536x; 1.3536x over previous
//
#include <hip/hip_runtime.h>
#include <math.h>

typedef float f32x4 __attribute__((ext_vector_type(4)));
typedef short short8 __attribute__((ext_vector_type(8)));

__device__ __forceinline__ short bf16r(float f) {
    union { float f; unsigned u; } x; x.f = f;
    unsigned u = x.u + 0x7fffu + ((x.u >> 16) & 1u);
    return (short)(u >> 16);
}

// ---------------------------------------------------------------------------
// pack_kernel (16x16x32 format, verified r1-r9): B-frag lane holds
// B[k=8*(lane>>4)+i][n=lane&15]; one coalesced 16B/lane load per frag:
// wpack[(((c*K+j)*2+kb)*64+lane)*8 + i]
//   = w2[co=c*16+(lane&15)][ci=kb*32+8*((lane>>4)&3)+i][j]
// ---------------------------------------------------------------------------
template<int K>
__device__ __forceinline__ void pack_branch(const float* __restrict__ w2,
                                            short* __restrict__ wpack, int u) {
    int lane = u & 63;
    int kb   = (u >> 6) & 1;
    int rem  = u >> 7;          // c*K + j
    int j = rem % K, c = rem / K;
    int co  = c * 16 + (lane & 15);
    int cib = kb * 32 + 8 * ((lane >> 4) & 3);
    short8 v;
    #pragma unroll
    for (int i = 0; i < 8; ++i)
        v[i] = bf16r(w2[(co * 64 + (cib + i)) * K + j]);
    *reinterpret_cast<short8*>(wpack + (size_t)u * 8) = v;
}

__global__ __launch_bounds__(256) void pack_kernel(
    const float* __restrict__ w23, const float* __restrict__ w25,
    const float* __restrict__ w27,
    short* __restrict__ wp3, short* __restrict__ wp5, short* __restrict__ wp7)
{
    int tid = blockIdx.x * 256 + threadIdx.x;
    const int n3 = 8 * 3 * 2 * 64;   // 3072
    const int n5 = 8 * 5 * 2 * 64;   // 5120
    const int n7 = 8 * 7 * 2 * 64;   // 7168
    if (tid < n3)                pack_branch<3>(w23, wp3, tid);
    else if (tid < n3 + n5)      pack_branch<5>(w25, wp5, tid - n3);
    else if (tid < n3 + n5 + n7) pack_branch<7>(w27, wp7, tid - n3 - n5);
}

// ---------------------------------------------------------------------------
// mfma2c_pass<K,LT0,NLT>: one lt-pass over NLT tiles, TWO c-tiles per wave.
// ONE A-read (conflict-free swizzle, lt as immediate offset) feeds TWO MFMAs.
// f32x4 static arrays (r8-proven register pattern).
// ---------------------------------------------------------------------------
template<int K, int LT0, int NLT>
__device__ __forceinline__ void mfma2c_pass(
    const short* t1s, const short* wpB0, const short* wpB1,
    int lane, f32x4* accA, f32x4* accB)
{
    constexpr int PAD = (K - 1) / 2;
    const int lane15 = lane & 15;
    const int g      = (lane >> 4) & 3;
    #pragma unroll
    for (int m = 0; m < 2 * K; ++m) {
        const int j = m >> 1, kb = m & 1;
        const short8 B0 = *reinterpret_cast<const short8*>(wpB0 + (size_t)m * 64 * 8);
        const short8 B1 = *reinterpret_cast<const short8*>(wpB1 + (size_t)m * 64 * 8);
        const int r   = LT0 * 16 + lane15 + 3 + j - PAD;
        const int col = (kb * 32 + 8 * g) ^ ((r & 7) << 3);   // lt-invariant swz
        const short* ab = &t1s[r * 64 + col];
        #pragma unroll
        for (int lt = 0; lt < NLT; ++lt) {
            const short8 af = *reinterpret_cast<const short8*>(ab + lt * 1024);
            accA[lt] = __builtin_amdgcn_mfma_f32_16x16x32_bf16(af, B0, accA[lt], 0, 0, 0);
            accB[lt] = __builtin_amdgcn_mfma_f32_16x16x32_bf16(af, B1, accB[lt], 0, 0, 0);
        }
    }
}

// pool_accum<GV,LT0,NLT>: C/D col=lane&15, row=4g+r4 (verified r1-r9).
template<int GV, int LT0, int NLT>
__device__ __forceinline__ void pool_accum(const f32x4* acc, float bb, float* pb) {
    #pragma unroll
    for (int lt = 0; lt < NLT; ++lt) {
        #pragma unroll
        for (int r4 = 0; r4 < 4; ++r4) {
            const int l = (LT0 + lt) * 16 + 4 * GV + r4;   // compile-time
            if (l < 200)
                pb[l / 20] += fmaxf(acc[lt][r4] + bb, 0.0f);
        }
    }
}

template<int K, int LT0, int NLT>
__device__ __forceinline__ void do_pass(
    const short* t1s, const short* wpB0, const short* wpB1, int lane,
    float bb0, float bb1, float* pb0, float* pb1)
{
    const int g = (lane >> 4) & 3;
    f32x4 accA[NLT], accB[NLT];
    #pragma unroll
    for (int i = 0; i < NLT; ++i) {
        f32x4 z = {0.f, 0.f, 0.f, 0.f};
        accA[i] = z; accB[i] = z;
    }
    mfma2c_pass<K, LT0, NLT>(t1s, wpB0, wpB1, lane, accA, accB);
    if      (g == 0) { pool_accum<0, LT0, NLT>(accA, bb0, pb0); pool_accum<0, LT0, NLT>(accB, bb1, pb1); }
    else if (g == 1) { pool_accum<1, LT0, NLT>(accA, bb0, pb0); pool_accum<1, LT0, NLT>(accB, bb1, pb1); }
    else if (g == 2) { pool_accum<2, LT0, NLT>(accA, bb0, pb0); pool_accum<2, LT0, NLT>(accB, bb1, pb1); }
    else             { pool_accum<3, LT0, NLT>(accA, bb0, pb0); pool_accum<3, LT0, NLT>(accB, bb1, pb1); }
}

// ---------------------------------------------------------------------------
// branch_body<K>: one (bn,branch), 256 threads / 4 waves; wave w owns
// c = 2w, 2w+1. conv1 -> t1s bf16 swizzled; MFMA in 3 lt-passes (5/4/4);
// register pooling + shfl(16/32) reduce -> pooled_s (linear, no atomics);
// coalesced xfc partial -> xfeatP_br[bn][32].
// ---------------------------------------------------------------------------
template<int K>
__device__ __forceinline__ void branch_body(
    const int bn, const int t,
    const float* __restrict__ x,
    const float* __restrict__ w1, const float* __restrict__ b1,
    const float* __restrict__ b2, const short* __restrict__ wpack,
    const float* __restrict__ w_xfc_br, float* __restrict__ xfeatP_br,
    float* xs, short* t1s, float* pooled_s, float* b2s)
{
    constexpr int PAD = (K - 1) / 2;
    const int lane = t & 63;
    const int w    = t >> 6;            // 0..3, owns c = 2w, 2w+1
    const int lane15 = lane & 15;

    // ---- P0: zero halos, preload b2 ----
    if (t < 208) xs[t] = 0.0f;
    for (int idx = t; idx < 32 * 64; idx += 256) {  // halo rows 0..2, 203..231
        int rr = idx >> 6;
        int row = (rr < 3) ? rr : (200 + rr);
        t1s[row * 64 + (idx & 63)] = 0;
    }
    if (t < 128) b2s[t] = b2[t];
    __syncthreads();

    if (t < 200) xs[3 + t] = x[bn * 200 + t];
    __syncthreads();

    // ---- P1: conv1 (ci = lane, l strided by 4 waves), bf16 swizzled write ----
    {
        float w1_0 = w1[lane * K + 0], w1_1 = w1[lane * K + 1], w1_2 = w1[lane * K + 2];
        float w1_3 = 0.f, w1_4 = 0.f, w1_5 = 0.f, w1_6 = 0.f;
        if (K > 3) { w1_3 = w1[lane * K + 3]; w1_4 = w1[lane * K + 4]; }
        if (K > 5) { w1_5 = w1[lane * K + 5]; w1_6 = w1[lane * K + 6]; }
        const float b1r = b1[lane];
        for (int l = w; l < 200; l += 4) {
            const float* xp = &xs[3 + l - PAD];
            float a = b1r;
            a = fmaf(w1_0, xp[0], a);
            a = fmaf(w1_1, xp[1], a);
            a = fmaf(w1_2, xp[2], a);
            if (K > 3) { a = fmaf(w1_3, xp[3], a); a = fmaf(w1_4, xp[4], a); }
            if (K > 5) { a = fmaf(w1_5, xp[5], a); a = fmaf(w1_6, xp[6], a); }
            const int row = l + 3;
            t1s[row * 64 + (lane ^ ((row & 7) << 3))] = bf16r(fmaxf(a, 0.0f));
        }
    }
    __syncthreads();

    // ---- P2: MFMA, 3 lt-passes, 2 c-tiles per wave ----
    const int c0 = 2 * w, c1 = 2 * w + 1;
    const int coA = c0 * 16 + lane15, coB = c1 * 16 + lane15;
    const float bb0 = b2s[coA], bb1 = b2s[coB];
    const short* wpB0 = wpack + ((size_t)(c0 * 2 * K) * 64 + lane) * 8;
    const short* wpB1 = wpack + ((size_t)(c1 * 2 * K) * 64 + lane) * 8;

    float pb0[10], pb1[10];
    #pragma unroll
    for (int b = 0; b < 10; ++b) { pb0[b] = 0.0f; pb1[b] = 0.0f; }

    do_pass<K, 0, 5>(t1s, wpB0, wpB1, lane, bb0, bb1, pb0, pb1);
    do_pass<K, 5, 4>(t1s, wpB0, wpB1, lane, bb0, bb1, pb0, pb1);
    do_pass<K, 9, 4>(t1s, wpB0, wpB1, lane, bb0, bb1, pb0, pb1);

    // ---- P3: reduce 4 co-sharing lanes; store pooled_s (linear, stride 10) ----
    #pragma unroll
    for (int b = 0; b < 10; ++b) {
        pb0[b] += __shfl_xor(pb0[b], 16);
        pb0[b] += __shfl_xor(pb0[b], 32);
        pb1[b] += __shfl_xor(pb1[b], 16);
        pb1[b] += __shfl_xor(pb1[b], 32);
    }
    if (lane < 16) {
        #pragma unroll
        for (int b = 0; b < 10; ++b) {
            pooled_s[coA * 10 + b] = pb0[b];
            pooled_s[coB * 10 + b] = pb1[b];
        }
    }
    __syncthreads();

    // ---- P4: xfc partial: o = t>>3, part = t&7; coalesced f32x4 ----
    {
        const int o = t >> 3, part = t & 7;
        const f32x4* wr4 = reinterpret_cast<const f32x4*>(w_xfc_br + o * 3840);
        const f32x4* pp4 = reinterpret_cast<const f32x4*>(pooled_s);
        float s0 = 0.0f, s1 = 0.0f;
        #pragma unroll
        for (int i = 0; i < 40; ++i) {
            const f32x4 wv = wr4[part + 8 * i];
            const f32x4 pv = pp4[part + 8 * i];
            float s = wv[0] * pv[0];
            s = fmaf(wv[1], pv[1], s);
            s = fmaf(wv[2], pv[2], s);
            s = fmaf(wv[3], pv[3], s);
            if (i & 1) s1 += s; else s0 += s;
        }
        float a = s0 + s1;
        a += __shfl_xor(a, 1);
        a += __shfl_xor(a, 2);
        a += __shfl_xor(a, 4);
        if (part == 0) xfeatP_br[bn * 32 + o] = a * 0.05f;
    }
}

__global__ __launch_bounds__(256, 4) void branch_fused(
    const float* __restrict__ x, const float* __restrict__ xmask,
    const float* __restrict__ w1_3, const float* __restrict__ b1_3,
    const float* __restrict__ b2_3, const short* __restrict__ wp3,
    const float* __restrict__ w1_5, const float* __restrict__ b1_5,
    const float* __restrict__ b2_5, const short* __restrict__ wp5,
    const float* __restrict__ w1_7, const float* __restrict__ b1_7,
    const float* __restrict__ b2_7, const short* __restrict__ wp7,
    const float* __restrict__ w_xfc, float* __restrict__ xfeatP)
{
    __shared__ float xs[208];
    __shared__ short t1s[232 * 64];
    __shared__ __align__(16) float pooled_s[1280];
    __shared__ float b2s[128];

    const int bx = blockIdx.x;
    const int br = bx % 3;
    const int bn = bx / 3;
    const int t  = threadIdx.x;

    if (xmask[bn] == 0.0f) return;      // tail multiplies row by 0 -> exact

    if (br == 0)
        branch_body<3>(bn, t, x, w1_3, b1_3, b2_3, wp3,
                       w_xfc,        xfeatP,             xs, t1s, pooled_s, b2s);
    else if (br == 1)
        branch_body<5>(bn, t, x, w1_5, b1_5, b2_5, wp5,
                       w_xfc + 1280, xfeatP + 512 * 32,  xs, t1s, pooled_s, b2s);
    else
        branch_body<7>(bn, t, x, w1_7, b1_7, b2_7, wp7,
                       w_xfc + 2560, xfeatP + 1024 * 32, xs, t1s, pooled_s, b2s);
}

// ---------------------------------------------------------------------------
// Tail: elements processor + fuse + 4-head attention + pool + regressor.
// One block per batch b (32 blocks). xfeat = (sum of 3 partials + b_xfc) *
// xmask — masked rows' unwritten (finite poison) partials zeroed exactly.
// ---------------------------------------------------------------------------
__global__ __launch_bounds__(256) void tail_kernel(
    const float* __restrict__ xfeatP,     // (3, 512, 32)
    const float* __restrict__ b_xfc,      // (32,)
    const float* __restrict__ xmaskp,     // (512,)
    const float* __restrict__ elem_info,  // (32, 16, 7)
    const float* __restrict__ emaskp,     // (32, 16)
    const float* __restrict__ w_float, const float* __restrict__ b_float,
    const float* __restrict__ atom_emb, const float* __restrict__ type_emb,
    const float* __restrict__ w_fuse,  const float* __restrict__ b_fuse,
    const float* __restrict__ in_w,    const float* __restrict__ in_b,
    const float* __restrict__ out_w,   const float* __restrict__ out_b,
    const float* __restrict__ w_fc1,   const float* __restrict__ b_fc1,
    const float* __restrict__ w_fc2,   const float* __restrict__ b_fc2,
    float* __restrict__ out)              // (32,)
{
    const int b = blockIdx.x;
    const int t = threadIdx.x;

    __shared__ float fu[16][60];
    __shared__ float fused[16][64];
    __shared__ float qkvs[16][192];
    __shared__ float sc[4][16][16];
    __shared__ float ao[16][64];
    __shared__ float aoo[16][64];
    __shared__ float p2s[64];
    __shared__ float hs[64];
    __shared__ float em[16];

    if (t < 16) em[t] = emaskp[b * 16 + t];
    for (int d = t; d < 512; d += 256) {
        int n = d >> 5, o = d & 31;
        const int bn = b * 16 + n;
        float a = xfeatP[bn * 32 + o]
                + xfeatP[(512 + bn) * 32 + o]
                + xfeatP[(1024 + bn) * 32 + o];
        fu[n][o] = (a + b_xfc[o]) * xmaskp[bn];
    }
    __syncthreads();

    {
        int n = t >> 4, slot = t & 15;
        float m  = em[n];
        float vE = (m >= 0.5f) ? 1.0f : 0.0f;
        const float* ei = elem_info + (b * 16 + n) * 7;
        float a = b_float[slot];
        #pragma unroll
        for (int i = 0; i < 5; ++i)
            a = fmaf(ei[i] * m, w_float[slot * 5 + i], a);
        fu[n][32 + slot] = fmaxf(a, 0.0f) * vE * m;

        int an = (int)(ei[5] * m);
        int et = (int)(ei[6] * m);
        float take = (vE != 0.0f && an >= 1 && an <= 94) ? 1.0f : 0.0f;
        int anc = an < 0 ? 0 : (an > 94 ? 94 : an);
        int etc = et < 0 ? 0 : (et > 5 ? 5 : et);
        if (slot < 8)
            fu[n][48 + slot] = atom_emb[anc * 8 + slot] * take * m;
        else if (slot < 12)
            fu[n][56 + (slot - 8)] = type_emb[etc * 4 + (slot - 8)] * take * m;
    }
    __syncthreads();

    for (int d = t; d < 1024; d += 256) {
        int n = d >> 6, o = d & 63;
        float a = b_fuse[o];
        const float* wr = w_fuse + o * 60;
        #pragma unroll
        for (int i = 0; i < 60; ++i) a = fmaf(fu[n][i], wr[i], a);
        fused[n][o] = a * em[n];
    }
    __syncthreads();

    for (int d = t; d < 3072; d += 256) {
        int n = d / 192, rr = d - n * 192;
        float a = in_b[rr];
        const float* wr = in_w + rr * 64;
        #pragma unroll
        for (int i = 0; i < 64; ++i) a = fmaf(fused[n][i], wr[i], a);
        qkvs[n][rr] = a;
    }
    __syncthreads();

    for (int d = t; d < 1024; d += 256) {
        int h = d >> 8, i = (d >> 4) & 15, j = d & 15;
        float a = 0.0f;
        #pragma unroll
        for (int dd = 0; dd < 16; ++dd)
            a = fmaf(qkvs[i][h * 16 + dd], qkvs[j][64 + h * 16 + dd], a);
        a *= 0.25f;
        if (em[j] < 0.5f) a = -1e30f;
        sc[h][i][j] = a;
    }
    __syncthreads();

    if (t < 64) {
        int h = t >> 4, i = t & 15;
        float mx = -3.4e38f;
        #pragma unroll
        for (int j = 0; j < 16; ++j) mx = fmaxf(mx, sc[h][i][j]);
        float e[16];
        float s = 0.0f;
        #pragma unroll
        for (int j = 0; j < 16; ++j) { e[j] = expf(sc[h][i][j] - mx); s += e[j]; }
        float inv = 1.0f / s;
        #pragma unroll
        for (int j = 0; j < 16; ++j) sc[h][i][j] = e[j] * inv;
    }
    __syncthreads();

    for (int d = t; d < 1024; d += 256) {
        int n = d >> 6, e = d & 63, h = e >> 4;
        float a = 0.0f;
        #pragma unroll
        for (int j = 0; j < 16; ++j)
            a = fmaf(sc[h][n][j], qkvs[j][128 + e], a);
        ao[n][e] = a;
    }
    __syncthreads();

    for (int d = t; d < 1024; d += 256) {
        int n = d >> 6, o = d & 63;
        float a = out_b[o];
        const float* wr = out_w + o * 64;
        #pragma unroll
        for (int i = 0; i < 64; ++i) a = fmaf(ao[n][i], wr[i], a);
        aoo[n][o] = a * em[n];
    }
    __syncthreads();

    if (t < 64) {
        float s = 0.0f, ms = 0.0f;
        #pragma unroll
        for (int n = 0; n < 16; ++n) { s += aoo[n][t]; ms += em[n]; }
        p2s[t] = s / (ms + 1e-8f);
    }
    __syncthreads();

    if (t < 64) {
        float a = b_fc1[t];
        const float* wr = w_fc1 + t * 64;
        #pragma unroll
        for (int i = 0; i < 64; ++i) a = fmaf(p2s[i], wr[i], a);
        hs[t] = fmaxf(a, 0.0f);
    }
    __syncthreads();

    if (t < 64) {
        float v = hs[t] * w_fc2[t];
        #pragma unroll
        for (int d2 = 32; d2 >= 1; d2 >>= 1) v += __shfl_xor(v, d2);
        if (t == 0) out[b] = v + b_fc2[0];
    }
}

extern "C" void kernel_launch(void* const* d_in, const int* in_sizes, int n_in,
                              void* d_out, int out_size, void* d_ws, size_t ws_size,
                              hipStream_t stream)
{
    (void)in_sizes; (void)n_in; (void)out_size; (void)ws_size;
    const float* x     = (const float*)d_in[0];
    const float* xmask = (const float*)d_in[1];
    const float* einfo = (const float*)d_in[2];
    const float* emask = (const float*)d_in[3];

    float* xfeatP = (float*)d_ws;                 // 3*512*32 f32 = 196.6 KB
    short* wp3 = (short*)(xfeatP + 3 * 512 * 32); // 3072*8 shorts
    short* wp5 = wp3 + 24576;                     // 5120*8 shorts
    short* wp7 = wp5 + 40960;                     // 7168*8 shorts

    pack_kernel<<<60, 256, 0, stream>>>(
        (const float*)d_in[6], (const float*)d_in[10], (const float*)d_in[14],
        wp3, wp5, wp7);

    branch_fused<<<1536, 256, 0, stream>>>(x, xmask,
        (const float*)d_in[4],  (const float*)d_in[5],  (const float*)d_in[7],  wp3,
        (const float*)d_in[8],  (const float*)d_in[9],  (const float*)d_in[11], wp5,
        (const float*)d_in[12], (const float*)d_in[13], (const float*)d_in[15], wp7,
        (const float*)d_in[16], xfeatP);

    tail_kernel<<<32, 256, 0, stream>>>(xfeatP,
        (const float*)d_in[17], xmask, einfo, emask,
        (const float*)d_in[18], (const float*)d_in[19],
        (const float*)d_in[20], (const float*)d_in[21],
        (const float*)d_in[22], (const float*)d_in[23],
        (const float*)d_in[24], (const float*)d_in[25],
        (const float*)d_in[26], (const float*)d_in[27],
        (const float*)d_in[28], (const float*)d_in[29],
        (const float*)d_in[30], (const float*)d_in[31],
        (float*)d_out);
}

// Round 12
// 72.576 us; speedup vs baseline: 1.6191x; 1.1961x over previous
//
#include <hip/hip_runtime.h>
#include <math.h>

typedef float f32x4 __attribute__((ext_vector_type(4)));
typedef short short8 __attribute__((ext_vector_type(8)));

__device__ __forceinline__ short bf16r(float f) {
    union { float f; unsigned u; } x; x.f = f;
    unsigned u = x.u + 0x7fffu + ((x.u >> 16) & 1u);
    return (short)(u >> 16);
}

// ---------------------------------------------------------------------------
// pack_kernel (16x16x32 format, verified r1-r11): B-frag lane holds
// B[k=8*(lane>>4)+i][n=lane&15]; one coalesced 16B/lane load per frag:
// wpack[(((c*K+j)*2+kb)*64+lane)*8 + i]
//   = w2[co=c*16+(lane&15)][ci=kb*32+8*((lane>>4)&3)+i][j]
// ---------------------------------------------------------------------------
template<int K>
__device__ __forceinline__ void pack_branch(const float* __restrict__ w2,
                                            short* __restrict__ wpack, int u) {
    int lane = u & 63;
    int kb   = (u >> 6) & 1;
    int rem  = u >> 7;          // c*K + j
    int j = rem % K, c = rem / K;
    int co  = c * 16 + (lane & 15);
    int cib = kb * 32 + 8 * ((lane >> 4) & 3);
    short8 v;
    #pragma unroll
    for (int i = 0; i < 8; ++i)
        v[i] = bf16r(w2[(co * 64 + (cib + i)) * K + j]);
    *reinterpret_cast<short8*>(wpack + (size_t)u * 8) = v;
}

__global__ __launch_bounds__(256) void pack_kernel(
    const float* __restrict__ w23, const float* __restrict__ w25,
    const float* __restrict__ w27,
    short* __restrict__ wp3, short* __restrict__ wp5, short* __restrict__ wp7)
{
    int tid = blockIdx.x * 256 + threadIdx.x;
    const int n3 = 8 * 3 * 2 * 64;   // 3072
    const int n5 = 8 * 5 * 2 * 64;   // 5120
    const int n7 = 8 * 7 * 2 * 64;   // 7168
    if (tid < n3)                pack_branch<3>(w23, wp3, tid);
    else if (tid < n3 + n5)      pack_branch<5>(w25, wp5, tid - n3);
    else if (tid < n3 + n5 + n7) pack_branch<7>(w27, wp7, tid - n3 - n5);
}

// ---------------------------------------------------------------------------
// pool_accum<GV>: relu'd accumulator elements -> 10 pool bins; GV compile-time
// so pb[] is statically indexed (registers). Verified r7-r8.
// ---------------------------------------------------------------------------
template<int GV>
__device__ __forceinline__ void pool_accum(const f32x4* acc, float bb, float* pb) {
    #pragma unroll
    for (int lt = 0; lt < 13; ++lt) {
        #pragma unroll
        for (int r4 = 0; r4 < 4; ++r4) {
            const int l = lt * 16 + 4 * GV + r4;   // compile-time
            if (l < 200)
                pb[l / 20] += fmaxf(acc[lt][r4] + bb, 0.0f);
        }
    }
}

// ---------------------------------------------------------------------------
// branch_body<K>: one (bn,branch), 512 threads / 8 waves, wave w owns c = w.
// EXACT r8 MFMA codegen (the only structure measured spill-free at this
// register demand): (j,kb) outer fully unrolled, ONE B-load per group
// (load-use-discard), 13 independent f32x4 acc chains with lt as immediate
// ds offsets (swizzle lt-invariant). Atomic-free pooling; coalesced f32x4
// xfc partial (r11's) -> xfeatP_br[bn][32].
// ---------------------------------------------------------------------------
template<int K>
__device__ __forceinline__ void branch_body(
    const int bn, const int t,
    const float* __restrict__ x,
    const float* __restrict__ w1, const float* __restrict__ b1,
    const float* __restrict__ b2, const short* __restrict__ wpack,
    const float* __restrict__ w_xfc_br, float* __restrict__ xfeatP_br,
    float* xs, short* t1s, float* pooled_s, float* b2s)
{
    constexpr int PAD = (K - 1) / 2;
    const int lane = t & 63;
    const int w    = t >> 6;            // 0..7 = c
    const int lane15 = lane & 15;
    const int g      = (lane >> 4) & 3;

    // ---- P0: zero halos, preload b2 ----
    if (t < 208) xs[t] = 0.0f;
    for (int idx = t; idx < 32 * 64; idx += 512) {  // halo rows 0..2, 203..231
        int rr = idx >> 6;
        int row = (rr < 3) ? rr : (200 + rr);
        t1s[row * 64 + (idx & 63)] = 0;
    }
    if (t < 128) b2s[t] = b2[t];
    __syncthreads();

    if (t < 200) xs[3 + t] = x[bn * 200 + t];
    __syncthreads();

    // ---- P1: conv1 (ci = lane, l strided by 8 waves), bf16 swizzled write ----
    {
        float w1_0 = w1[lane * K + 0], w1_1 = w1[lane * K + 1], w1_2 = w1[lane * K + 2];
        float w1_3 = 0.f, w1_4 = 0.f, w1_5 = 0.f, w1_6 = 0.f;
        if (K > 3) { w1_3 = w1[lane * K + 3]; w1_4 = w1[lane * K + 4]; }
        if (K > 5) { w1_5 = w1[lane * K + 5]; w1_6 = w1[lane * K + 6]; }
        const float b1r = b1[lane];
        for (int l = w; l < 200; l += 8) {
            const float* xp = &xs[3 + l - PAD];
            float a = b1r;
            a = fmaf(w1_0, xp[0], a);
            a = fmaf(w1_1, xp[1], a);
            a = fmaf(w1_2, xp[2], a);
            if (K > 3) { a = fmaf(w1_3, xp[3], a); a = fmaf(w1_4, xp[4], a); }
            if (K > 5) { a = fmaf(w1_5, xp[5], a); a = fmaf(w1_6, xp[6], a); }
            const int row = l + 3;
            t1s[row * 64 + (lane ^ ((row & 7) << 3))] = bf16r(fmaxf(a, 0.0f));
        }
    }
    __syncthreads();

    // ---- P2: MFMA. Wave w owns c = w; 13 chains per (j,kb) group. ----
    const int co = w * 16 + lane15;
    const float bb = b2s[co];
    f32x4 acc[13];
    #pragma unroll
    for (int lt = 0; lt < 13; ++lt) {
        f32x4 z = {0.f, 0.f, 0.f, 0.f};
        acc[lt] = z;
    }
    {
        const short* wpB = wpack + ((size_t)(w * 2 * K) * 64 + lane) * 8;
        #pragma unroll
        for (int j = 0; j < K; ++j) {
            #pragma unroll
            for (int kb = 0; kb < 2; ++kb) {
                const short8 bfr = *reinterpret_cast<const short8*>(
                    wpB + (size_t)(j * 2 + kb) * 64 * 8);
                const int r0  = lane15 + 3 + j - PAD;                // row for lt=0
                const int col = (kb * 32 + 8 * g) ^ ((r0 & 7) << 3); // lt-invariant
                const short* abase = &t1s[r0 * 64 + col];
                #pragma unroll
                for (int lt = 0; lt < 13; ++lt) {
                    acc[lt] = __builtin_amdgcn_mfma_f32_16x16x32_bf16(
                        *reinterpret_cast<const short8*>(abase + lt * 1024),
                        bfr, acc[lt], 0, 0, 0);
                }
            }
        }
    }

    // ---- P3: atomic-free pooling -> pooled_s[co*10 + bin] (linear) ----
    {
        float pb[10];
        #pragma unroll
        for (int b = 0; b < 10; ++b) pb[b] = 0.0f;
        if      (g == 0) pool_accum<0>(acc, bb, pb);
        else if (g == 1) pool_accum<1>(acc, bb, pb);
        else if (g == 2) pool_accum<2>(acc, bb, pb);
        else             pool_accum<3>(acc, bb, pb);
        #pragma unroll
        for (int b = 0; b < 10; ++b) {
            pb[b] += __shfl_xor(pb[b], 16);
            pb[b] += __shfl_xor(pb[b], 32);
        }
        if (lane < 16) {
            #pragma unroll
            for (int b = 0; b < 10; ++b)
                pooled_s[co * 10 + b] = pb[b];   // 16 distinct banks, no conflict
        }
    }
    __syncthreads();

    // ---- P4: xfc partial: o = t>>4 (0..31), part = t&15; coalesced f32x4 ----
    {
        const int o = t >> 4, part = t & 15;
        const f32x4* wr4 = reinterpret_cast<const f32x4*>(w_xfc_br + o * 3840);
        const f32x4* pp4 = reinterpret_cast<const f32x4*>(pooled_s);
        float s0 = 0.0f, s1 = 0.0f;
        #pragma unroll
        for (int i = 0; i < 20; ++i) {
            const f32x4 wv = wr4[part + 16 * i];
            const f32x4 pv = pp4[part + 16 * i];
            float s = wv[0] * pv[0];
            s = fmaf(wv[1], pv[1], s);
            s = fmaf(wv[2], pv[2], s);
            s = fmaf(wv[3], pv[3], s);
            if (i & 1) s1 += s; else s0 += s;
        }
        float a = s0 + s1;
        a += __shfl_xor(a, 1);
        a += __shfl_xor(a, 2);
        a += __shfl_xor(a, 4);
        a += __shfl_xor(a, 8);
        if (part == 0) xfeatP_br[bn * 32 + o] = a * 0.05f;
    }
}

__global__ __launch_bounds__(512) void branch_fused(
    const float* __restrict__ x, const float* __restrict__ xmask,
    const float* __restrict__ w1_3, const float* __restrict__ b1_3,
    const float* __restrict__ b2_3, const short* __restrict__ wp3,
    const float* __restrict__ w1_5, const float* __restrict__ b1_5,
    const float* __restrict__ b2_5, const short* __restrict__ wp5,
    const float* __restrict__ w1_7, const float* __restrict__ b1_7,
    const float* __restrict__ b2_7, const short* __restrict__ wp7,
    const float* __restrict__ w_xfc, float* __restrict__ xfeatP)
{
    __shared__ float xs[208];
    __shared__ short t1s[232 * 64];
    __shared__ __align__(16) float pooled_s[1280];
    __shared__ float b2s[128];

    const int bx = blockIdx.x;
    const int br = bx % 3;          // interleave K=3/5/7 in every generation
    const int bn = bx / 3;
    const int t  = threadIdx.x;

    if (xmask[bn] == 0.0f) return;  // tail multiplies row by 0 -> exact

    if (br == 0)
        branch_body<3>(bn, t, x, w1_3, b1_3, b2_3, wp3,
                       w_xfc,        xfeatP,             xs, t1s, pooled_s, b2s);
    else if (br == 1)
        branch_body<5>(bn, t, x, w1_5, b1_5, b2_5, wp5,
                       w_xfc + 1280, xfeatP + 512 * 32,  xs, t1s, pooled_s, b2s);
    else
        branch_body<7>(bn, t, x, w1_7, b1_7, b2_7, wp7,
                       w_xfc + 2560, xfeatP + 1024 * 32, xs, t1s, pooled_s, b2s);
}

// ---------------------------------------------------------------------------
// Tail: elements processor + fuse + 4-head attention + pool + regressor.
// One block per batch b (32 blocks). xfeat = (sum of 3 partials + b_xfc) *
// xmask — masked rows' unwritten (finite poison) partials zeroed exactly.
// ---------------------------------------------------------------------------
__global__ __launch_bounds__(256) void tail_kernel(
    const float* __restrict__ xfeatP,     // (3, 512, 32)
    const float* __restrict__ b_xfc,      // (32,)
    const float* __restrict__ xmaskp,     // (512,)
    const float* __restrict__ elem_info,  // (32, 16, 7)
    const float* __restrict__ emaskp,     // (32, 16)
    const float* __restrict__ w_float, const float* __restrict__ b_float,
    const float* __restrict__ atom_emb, const float* __restrict__ type_emb,
    const float* __restrict__ w_fuse,  const float* __restrict__ b_fuse,
    const float* __restrict__ in_w,    const float* __restrict__ in_b,
    const float* __restrict__ out_w,   const float* __restrict__ out_b,
    const float* __restrict__ w_fc1,   const float* __restrict__ b_fc1,
    const float* __restrict__ w_fc2,   const float* __restrict__ b_fc2,
    float* __restrict__ out)              // (32,)
{
    const int b = blockIdx.x;
    const int t = threadIdx.x;

    __shared__ float fu[16][60];
    __shared__ float fused[16][64];
    __shared__ float qkvs[16][192];
    __shared__ float sc[4][16][16];
    __shared__ float ao[16][64];
    __shared__ float aoo[16][64];
    __shared__ float p2s[64];
    __shared__ float hs[64];
    __shared__ float em[16];

    if (t < 16) em[t] = emaskp[b * 16 + t];
    for (int d = t; d < 512; d += 256) {
        int n = d >> 5, o = d & 31;
        const int bn = b * 16 + n;
        float a = xfeatP[bn * 32 + o]
                + xfeatP[(512 + bn) * 32 + o]
                + xfeatP[(1024 + bn) * 32 + o];
        fu[n][o] = (a + b_xfc[o]) * xmaskp[bn];
    }
    __syncthreads();

    {
        int n = t >> 4, slot = t & 15;
        float m  = em[n];
        float vE = (m >= 0.5f) ? 1.0f : 0.0f;
        const float* ei = elem_info + (b * 16 + n) * 7;
        float a = b_float[slot];
        #pragma unroll
        for (int i = 0; i < 5; ++i)
            a = fmaf(ei[i] * m, w_float[slot * 5 + i], a);
        fu[n][32 + slot] = fmaxf(a, 0.0f) * vE * m;

        int an = (int)(ei[5] * m);
        int et = (int)(ei[6] * m);
        float take = (vE != 0.0f && an >= 1 && an <= 94) ? 1.0f : 0.0f;
        int anc = an < 0 ? 0 : (an > 94 ? 94 : an);
        int etc = et < 0 ? 0 : (et > 5 ? 5 : et);
        if (slot < 8)
            fu[n][48 + slot] = atom_emb[anc * 8 + slot] * take * m;
        else if (slot < 12)
            fu[n][56 + (slot - 8)] = type_emb[etc * 4 + (slot - 8)] * take * m;
    }
    __syncthreads();

    for (int d = t; d < 1024; d += 256) {
        int n = d >> 6, o = d & 63;
        float a = b_fuse[o];
        const float* wr = w_fuse + o * 60;
        #pragma unroll
        for (int i = 0; i < 60; ++i) a = fmaf(fu[n][i], wr[i], a);
        fused[n][o] = a * em[n];
    }
    __syncthreads();

    for (int d = t; d < 3072; d += 256) {
        int n = d / 192, rr = d - n * 192;
        float a = in_b[rr];
        const float* wr = in_w + rr * 64;
        #pragma unroll
        for (int i = 0; i < 64; ++i) a = fmaf(fused[n][i], wr[i], a);
        qkvs[n][rr] = a;
    }
    __syncthreads();

    for (int d = t; d < 1024; d += 256) {
        int h = d >> 8, i = (d >> 4) & 15, j = d & 15;
        float a = 0.0f;
        #pragma unroll
        for (int dd = 0; dd < 16; ++dd)
            a = fmaf(qkvs[i][h * 16 + dd], qkvs[j][64 + h * 16 + dd], a);
        a *= 0.25f;
        if (em[j] < 0.5f) a = -1e30f;
        sc[h][i][j] = a;
    }
    __syncthreads();

    if (t < 64) {
        int h = t >> 4, i = t & 15;
        float mx = -3.4e38f;
        #pragma unroll
        for (int j = 0; j < 16; ++j) mx = fmaxf(mx, sc[h][i][j]);
        float e[16];
        float s = 0.0f;
        #pragma unroll
        for (int j = 0; j < 16; ++j) { e[j] = expf(sc[h][i][j] - mx); s += e[j]; }
        float inv = 1.0f / s;
        #pragma unroll
        for (int j = 0; j < 16; ++j) sc[h][i][j] = e[j] * inv;
    }
    __syncthreads();

    for (int d = t; d < 1024; d += 256) {
        int n = d >> 6, e = d & 63, h = e >> 4;
        float a = 0.0f;
        #pragma unroll
        for (int j = 0; j < 16; ++j)
            a = fmaf(sc[h][n][j], qkvs[j][128 + e], a);
        ao[n][e] = a;
    }
    __syncthreads();

    for (int d = t; d < 1024; d += 256) {
        int n = d >> 6, o = d & 63;
        float a = out_b[o];
        const float* wr = out_w + o * 64;
        #pragma unroll
        for (int i = 0; i < 64; ++i) a = fmaf(ao[n][i], wr[i], a);
        aoo[n][o] = a * em[n];
    }
    __syncthreads();

    if (t < 64) {
        float s = 0.0f, ms = 0.0f;
        #pragma unroll
        for (int n = 0; n < 16; ++n) { s += aoo[n][t]; ms += em[n]; }
        p2s[t] = s / (ms + 1e-8f);
    }
    __syncthreads();

    if (t < 64) {
        float a = b_fc1[t];
        const float* wr = w_fc1 + t * 64;
        #pragma unroll
        for (int i = 0; i < 64; ++i) a = fmaf(p2s[i], wr[i], a);
        hs[t] = fmaxf(a, 0.0f);
    }
    __syncthreads();

    if (t < 64) {
        float v = hs[t] * w_fc2[t];
        #pragma unroll
        for (int d2 = 32; d2 >= 1; d2 >>= 1) v += __shfl_xor(v, d2);
        if (t == 0) out[b] = v + b_fc2[0];
    }
}

extern "C" void kernel_launch(void* const* d_in, const int* in_sizes, int n_in,
                              void* d_out, int out_size, void* d_ws, size_t ws_size,
                              hipStream_t stream)
{
    (void)in_sizes; (void)n_in; (void)out_size; (void)ws_size;
    const float* x     = (const float*)d_in[0];
    const float* xmask = (const float*)d_in[1];
    const float* einfo = (const float*)d_in[2];
    const float* emask = (const float*)d_in[3];

    float* xfeatP = (float*)d_ws;                 // 3*512*32 f32 = 196.6 KB
    short* wp3 = (short*)(xfeatP + 3 * 512 * 32); // 3072*8 shorts
    short* wp5 = wp3 + 24576;                     // 5120*8 shorts
    short* wp7 = wp5 + 40960;                     // 7168*8 shorts

    pack_kernel<<<60, 256, 0, stream>>>(
        (const float*)d_in[6], (const float*)d_in[10], (const float*)d_in[14],
        wp3, wp5, wp7);

    branch_fused<<<1536, 512, 0, stream>>>(x, xmask,
        (const float*)d_in[4],  (const float*)d_in[5],  (const float*)d_in[7],  wp3,
        (const float*)d_in[8],  (const float*)d_in[9],  (const float*)d_in[11], wp5,
        (const float*)d_in[12], (const float*)d_in[13], (const float*)d_in[15], wp7,
        (const float*)d_in[16], xfeatP);

    tail_kernel<<<32, 256, 0, stream>>>(xfeatP,
        (const float*)d_in[17], xmask, einfo, emask,
        (const float*)d_in[18], (const float*)d_in[19],
        (const float*)d_in[20], (const float*)d_in[21],
        (const float*)d_in[22], (const float*)d_in[23],
        (const float*)d_in[24], (const float*)d_in[25],
        (const float*)d_in[26], (const float*)d_in[27],
        (const float*)d_in[28], (const float*)d_in[29],
        (const float*)d_in[30], (const float*)d_in[31],
        (float*)d_out);
}

// Round 13
// 71.690 us; speedup vs baseline: 1.6392x; 1.0124x over previous
//
#include <hip/hip_runtime.h>
#include <math.h>

typedef float f32x4 __attribute__((ext_vector_type(4)));
typedef short short8 __attribute__((ext_vector_type(8)));

__device__ __forceinline__ short bf16r(float f) {
    union { float f; unsigned u; } x; x.f = f;
    unsigned u = x.u + 0x7fffu + ((x.u >> 16) & 1u);
    return (short)(u >> 16);
}

// ---------------------------------------------------------------------------
// pack_kernel (16x16x32 format, verified r1-r12): B-frag lane holds
// B[k=8*(lane>>4)+i][n=lane&15]; one coalesced 16B/lane load per frag:
// wpack[(((c*K+j)*2+kb)*64+lane)*8 + i]
//   = w2[co=c*16+(lane&15)][ci=kb*32+8*((lane>>4)&3)+i][j]
// ---------------------------------------------------------------------------
template<int K>
__device__ __forceinline__ void pack_branch(const float* __restrict__ w2,
                                            short* __restrict__ wpack, int u) {
    int lane = u & 63;
    int kb   = (u >> 6) & 1;
    int rem  = u >> 7;          // c*K + j
    int j = rem % K, c = rem / K;
    int co  = c * 16 + (lane & 15);
    int cib = kb * 32 + 8 * ((lane >> 4) & 3);
    short8 v;
    #pragma unroll
    for (int i = 0; i < 8; ++i)
        v[i] = bf16r(w2[(co * 64 + (cib + i)) * K + j]);
    *reinterpret_cast<short8*>(wpack + (size_t)u * 8) = v;
}

__global__ __launch_bounds__(256) void pack_kernel(
    const float* __restrict__ w23, const float* __restrict__ w25,
    const float* __restrict__ w27,
    short* __restrict__ wp3, short* __restrict__ wp5, short* __restrict__ wp7)
{
    int tid = blockIdx.x * 256 + threadIdx.x;
    const int n3 = 8 * 3 * 2 * 64;   // 3072
    const int n5 = 8 * 5 * 2 * 64;   // 5120
    const int n7 = 8 * 7 * 2 * 64;   // 7168
    if (tid < n3)                pack_branch<3>(w23, wp3, tid);
    else if (tid < n3 + n5)      pack_branch<5>(w25, wp5, tid - n3);
    else if (tid < n3 + n5 + n7) pack_branch<7>(w27, wp7, tid - n3 - n5);
}

// ---------------------------------------------------------------------------
// mfma_pass2<K,LT0,NLT>: dual-c lt-pass. m-loop NOT unrolled (unroll 1) so
// B-loads cannot be hoisted en masse (the r10/r11 spill cause); named 1-deep
// B prefetch (bA/bB -> nA/nB) hides L2 latency. One A-read feeds 2 MFMAs.
// ---------------------------------------------------------------------------
template<int K, int LT0, int NLT>
__device__ __forceinline__ void mfma_pass2(
    const short* __restrict__ t1s,
    const short8* __restrict__ wpB0, const short8* __restrict__ wpB1,
    int lane, f32x4* accA, f32x4* accB)
{
    constexpr int PAD = (K - 1) / 2;
    const int lane15 = lane & 15;
    const int g8 = 8 * ((lane >> 4) & 3);
    short8 bA = wpB0[0], bB = wpB1[0];
    #pragma unroll 1
    for (int m = 0; m < 2 * K - 1; ++m) {
        const short8 nA = wpB0[(m + 1) * 64];
        const short8 nB = wpB1[(m + 1) * 64];
        const int j = m >> 1, kb = m & 1;
        const int r = LT0 * 16 + lane15 + 3 + j - PAD;
        const int col = (kb * 32 + g8) ^ ((r & 7) << 3);
        const short* ab = &t1s[r * 64 + col];
        #pragma unroll
        for (int lt = 0; lt < NLT; ++lt) {
            const short8 af = *reinterpret_cast<const short8*>(ab + lt * 1024);
            accA[lt] = __builtin_amdgcn_mfma_f32_16x16x32_bf16(af, bA, accA[lt], 0, 0, 0);
            accB[lt] = __builtin_amdgcn_mfma_f32_16x16x32_bf16(af, bB, accB[lt], 0, 0, 0);
        }
        bA = nA; bB = nB;
    }
    {   // peeled last group
        const int m = 2 * K - 1;
        const int j = m >> 1, kb = m & 1;
        const int r = LT0 * 16 + lane15 + 3 + j - PAD;
        const int col = (kb * 32 + g8) ^ ((r & 7) << 3);
        const short* ab = &t1s[r * 64 + col];
        #pragma unroll
        for (int lt = 0; lt < NLT; ++lt) {
            const short8 af = *reinterpret_cast<const short8*>(ab + lt * 1024);
            accA[lt] = __builtin_amdgcn_mfma_f32_16x16x32_bf16(af, bA, accA[lt], 0, 0, 0);
            accB[lt] = __builtin_amdgcn_mfma_f32_16x16x32_bf16(af, bB, accB[lt], 0, 0, 0);
        }
    }
}

// pool_accum<GV,LT0,NLT>: C/D col=lane&15, row=4g+r4 (verified r1-r12).
template<int GV, int LT0, int NLT>
__device__ __forceinline__ void pool_accum(const f32x4* acc, float bb, float* pb) {
    #pragma unroll
    for (int lt = 0; lt < NLT; ++lt) {
        #pragma unroll
        for (int r4 = 0; r4 < 4; ++r4) {
            const int l = (LT0 + lt) * 16 + 4 * GV + r4;   // compile-time
            if (l < 200)
                pb[l / 20] += fmaxf(acc[lt][r4] + bb, 0.0f);
        }
    }
}

template<int K, int LT0, int NLT>
__device__ __forceinline__ void do_pass2(
    const short* __restrict__ t1s,
    const short8* __restrict__ wpB0, const short8* __restrict__ wpB1,
    int lane, float bb0, float bb1, float* pb0, float* pb1)
{
    const int g = (lane >> 4) & 3;
    f32x4 accA[NLT], accB[NLT];
    #pragma unroll
    for (int i = 0; i < NLT; ++i) {
        f32x4 z = {0.f, 0.f, 0.f, 0.f};
        accA[i] = z; accB[i] = z;
    }
    mfma_pass2<K, LT0, NLT>(t1s, wpB0, wpB1, lane, accA, accB);
    if      (g == 0) { pool_accum<0, LT0, NLT>(accA, bb0, pb0); pool_accum<0, LT0, NLT>(accB, bb1, pb1); }
    else if (g == 1) { pool_accum<1, LT0, NLT>(accA, bb0, pb0); pool_accum<1, LT0, NLT>(accB, bb1, pb1); }
    else if (g == 2) { pool_accum<2, LT0, NLT>(accA, bb0, pb0); pool_accum<2, LT0, NLT>(accB, bb1, pb1); }
    else             { pool_accum<3, LT0, NLT>(accA, bb0, pb0); pool_accum<3, LT0, NLT>(accB, bb1, pb1); }
}

// ---------------------------------------------------------------------------
// branch_body<K>: one (bn,branch), 256 threads / 4 waves; wave w owns
// c = 2w, 2w+1. conv1 via wave-uniform register-window (31 broadcast b32
// reads per 25-l chunk, 5.6x fewer LDS instrs); MFMA in 2 lt-passes (7/6);
// atomic-free pooling; coalesced f32x4 xfc partial -> xfeatP_br[bn][32].
// ---------------------------------------------------------------------------
template<int K>
__device__ __forceinline__ void branch_body(
    const int bn, const int t,
    const float* __restrict__ x,
    const float* __restrict__ w1, const float* __restrict__ b1,
    const float* __restrict__ b2, const short* __restrict__ wpack,
    const float* __restrict__ w_xfc_br, float* __restrict__ xfeatP_br,
    float* xs, short* t1s, float* pooled_s, float* b2s)
{
    constexpr int PAD = (K - 1) / 2;
    const int lane = t & 63;
    const int w    = t >> 6;            // 0..3, owns c = 2w, 2w+1
    const int lane15 = lane & 15;

    // ---- P0: zero halos, preload b2 ----
    if (t < 208) xs[t] = 0.0f;
    for (int idx = t; idx < 32 * 64; idx += 256) {  // halo rows 0..2, 203..231
        int rr = idx >> 6;
        int row = (rr < 3) ? rr : (200 + rr);
        t1s[row * 64 + (idx & 63)] = 0;
    }
    if (t < 128) b2s[t] = b2[t];
    __syncthreads();

    if (t < 200) xs[3 + t] = x[bn * 200 + t];
    __syncthreads();

    // ---- P1: conv1, register-window. Wave w covers l in [50w, 50w+50),
    // two sequential 25-l chunks; xr[] static-indexed (registers). ----
    {
        float w1_0 = w1[lane * K + 0], w1_1 = w1[lane * K + 1], w1_2 = w1[lane * K + 2];
        float w1_3 = 0.f, w1_4 = 0.f, w1_5 = 0.f, w1_6 = 0.f;
        if (K > 3) { w1_3 = w1[lane * K + 3]; w1_4 = w1[lane * K + 4]; }
        if (K > 5) { w1_5 = w1[lane * K + 5]; w1_6 = w1[lane * K + 6]; }
        const float b1r = b1[lane];
        #pragma unroll 1
        for (int ch = 0; ch < 2; ++ch) {
            const int lb = 50 * w + 25 * ch;       // wave-uniform base
            float xr[31];
            #pragma unroll
            for (int i = 0; i < 31; ++i) xr[i] = xs[lb + i];   // broadcast reads
            #pragma unroll
            for (int ll = 0; ll < 25; ++ll) {
                // xs idx = 3 + l + j - PAD = lb + (ll + 3 + j - PAD); all static
                float a = b1r;
                a = fmaf(w1_0, xr[ll + 3 - PAD + 0], a);
                a = fmaf(w1_1, xr[ll + 3 - PAD + 1], a);
                a = fmaf(w1_2, xr[ll + 3 - PAD + 2], a);
                if (K > 3) {
                    a = fmaf(w1_3, xr[ll + 3 - PAD + 3], a);
                    a = fmaf(w1_4, xr[ll + 3 - PAD + 4], a);
                }
                if (K > 5) {
                    a = fmaf(w1_5, xr[ll + 3 - PAD + 5], a);
                    a = fmaf(w1_6, xr[ll + 3 - PAD + 6], a);
                }
                const int row = lb + ll + 3;
                t1s[row * 64 + (lane ^ ((row & 7) << 3))] = bf16r(fmaxf(a, 0.0f));
            }
        }
    }
    __syncthreads();

    // ---- P2: MFMA, dual-c, two lt-passes (7 + 6) ----
    const int c0 = 2 * w, c1 = 2 * w + 1;
    const int coA = c0 * 16 + lane15, coB = c1 * 16 + lane15;
    const float bb0 = b2s[coA], bb1 = b2s[coB];
    const short8* wpB0 = reinterpret_cast<const short8*>(wpack)
                         + (size_t)(c0 * 2 * K) * 64 + lane;
    const short8* wpB1 = reinterpret_cast<const short8*>(wpack)
                         + (size_t)(c1 * 2 * K) * 64 + lane;

    float pb0[10], pb1[10];
    #pragma unroll
    for (int b = 0; b < 10; ++b) { pb0[b] = 0.0f; pb1[b] = 0.0f; }

    do_pass2<K, 0, 7>(t1s, wpB0, wpB1, lane, bb0, bb1, pb0, pb1);
    do_pass2<K, 7, 6>(t1s, wpB0, wpB1, lane, bb0, bb1, pb0, pb1);

    // ---- P3: reduce 4 co-sharing lanes; store pooled_s (linear) ----
    #pragma unroll
    for (int b = 0; b < 10; ++b) {
        pb0[b] += __shfl_xor(pb0[b], 16);
        pb0[b] += __shfl_xor(pb0[b], 32);
        pb1[b] += __shfl_xor(pb1[b], 16);
        pb1[b] += __shfl_xor(pb1[b], 32);
    }
    if (lane < 16) {
        #pragma unroll
        for (int b = 0; b < 10; ++b) {
            pooled_s[coA * 10 + b] = pb0[b];
            pooled_s[coB * 10 + b] = pb1[b];
        }
    }
    __syncthreads();

    // ---- P4: xfc partial: o = t>>3 (0..31), part = t&7; coalesced f32x4 ----
    {
        const int o = t >> 3, part = t & 7;
        const f32x4* wr4 = reinterpret_cast<const f32x4*>(w_xfc_br + o * 3840);
        const f32x4* pp4 = reinterpret_cast<const f32x4*>(pooled_s);
        float s0 = 0.0f, s1 = 0.0f;
        #pragma unroll
        for (int i = 0; i < 40; ++i) {
            const f32x4 wv = wr4[part + 8 * i];
            const f32x4 pv = pp4[part + 8 * i];
            float s = wv[0] * pv[0];
            s = fmaf(wv[1], pv[1], s);
            s = fmaf(wv[2], pv[2], s);
            s = fmaf(wv[3], pv[3], s);
            if (i & 1) s1 += s; else s0 += s;
        }
        float a = s0 + s1;
        a += __shfl_xor(a, 1);
        a += __shfl_xor(a, 2);
        a += __shfl_xor(a, 4);
        if (part == 0) xfeatP_br[bn * 32 + o] = a * 0.05f;
    }
}

__global__ __launch_bounds__(256, 4) void branch_fused(
    const float* __restrict__ x, const float* __restrict__ xmask,
    const float* __restrict__ w1_3, const float* __restrict__ b1_3,
    const float* __restrict__ b2_3, const short* __restrict__ wp3,
    const float* __restrict__ w1_5, const float* __restrict__ b1_5,
    const float* __restrict__ b2_5, const short* __restrict__ wp5,
    const float* __restrict__ w1_7, const float* __restrict__ b1_7,
    const float* __restrict__ b2_7, const short* __restrict__ wp7,
    const float* __restrict__ w_xfc, float* __restrict__ xfeatP)
{
    __shared__ float xs[208];
    __shared__ short t1s[232 * 64];
    __shared__ __align__(16) float pooled_s[1280];
    __shared__ float b2s[128];

    const int bx = blockIdx.x;
    const int br = bx % 3;          // interleave K=3/5/7 in every generation
    const int bn = bx / 3;
    const int t  = threadIdx.x;

    if (xmask[bn] == 0.0f) return;  // tail multiplies row by 0 -> exact

    if (br == 0)
        branch_body<3>(bn, t, x, w1_3, b1_3, b2_3, wp3,
                       w_xfc,        xfeatP,             xs, t1s, pooled_s, b2s);
    else if (br == 1)
        branch_body<5>(bn, t, x, w1_5, b1_5, b2_5, wp5,
                       w_xfc + 1280, xfeatP + 512 * 32,  xs, t1s, pooled_s, b2s);
    else
        branch_body<7>(bn, t, x, w1_7, b1_7, b2_7, wp7,
                       w_xfc + 2560, xfeatP + 1024 * 32, xs, t1s, pooled_s, b2s);
}

// ---------------------------------------------------------------------------
// Tail: elements processor + fuse + 4-head attention + pool + regressor.
// One block per batch b (32 blocks). xfeat = (sum of 3 partials + b_xfc) *
// xmask — masked rows' unwritten (finite poison) partials zeroed exactly.
// ---------------------------------------------------------------------------
__global__ __launch_bounds__(256) void tail_kernel(
    const float* __restrict__ xfeatP,     // (3, 512, 32)
    const float* __restrict__ b_xfc,      // (32,)
    const float* __restrict__ xmaskp,     // (512,)
    const float* __restrict__ elem_info,  // (32, 16, 7)
    const float* __restrict__ emaskp,     // (32, 16)
    const float* __restrict__ w_float, const float* __restrict__ b_float,
    const float* __restrict__ atom_emb, const float* __restrict__ type_emb,
    const float* __restrict__ w_fuse,  const float* __restrict__ b_fuse,
    const float* __restrict__ in_w,    const float* __restrict__ in_b,
    const float* __restrict__ out_w,   const float* __restrict__ out_b,
    const float* __restrict__ w_fc1,   const float* __restrict__ b_fc1,
    const float* __restrict__ w_fc2,   const float* __restrict__ b_fc2,
    float* __restrict__ out)              // (32,)
{
    const int b = blockIdx.x;
    const int t = threadIdx.x;

    __shared__ float fu[16][60];
    __shared__ float fused[16][64];
    __shared__ float qkvs[16][192];
    __shared__ float sc[4][16][16];
    __shared__ float ao[16][64];
    __shared__ float aoo[16][64];
    __shared__ float p2s[64];
    __shared__ float hs[64];
    __shared__ float em[16];

    if (t < 16) em[t] = emaskp[b * 16 + t];
    for (int d = t; d < 512; d += 256) {
        int n = d >> 5, o = d & 31;
        const int bn = b * 16 + n;
        float a = xfeatP[bn * 32 + o]
                + xfeatP[(512 + bn) * 32 + o]
                + xfeatP[(1024 + bn) * 32 + o];
        fu[n][o] = (a + b_xfc[o]) * xmaskp[bn];
    }
    __syncthreads();

    {
        int n = t >> 4, slot = t & 15;
        float m  = em[n];
        float vE = (m >= 0.5f) ? 1.0f : 0.0f;
        const float* ei = elem_info + (b * 16 + n) * 7;
        float a = b_float[slot];
        #pragma unroll
        for (int i = 0; i < 5; ++i)
            a = fmaf(ei[i] * m, w_float[slot * 5 + i], a);
        fu[n][32 + slot] = fmaxf(a, 0.0f) * vE * m;

        int an = (int)(ei[5] * m);
        int et = (int)(ei[6] * m);
        float take = (vE != 0.0f && an >= 1 && an <= 94) ? 1.0f : 0.0f;
        int anc = an < 0 ? 0 : (an > 94 ? 94 : an);
        int etc = et < 0 ? 0 : (et > 5 ? 5 : et);
        if (slot < 8)
            fu[n][48 + slot] = atom_emb[anc * 8 + slot] * take * m;
        else if (slot < 12)
            fu[n][56 + (slot - 8)] = type_emb[etc * 4 + (slot - 8)] * take * m;
    }
    __syncthreads();

    for (int d = t; d < 1024; d += 256) {
        int n = d >> 6, o = d & 63;
        float a = b_fuse[o];
        const float* wr = w_fuse + o * 60;
        #pragma unroll
        for (int i = 0; i < 60; ++i) a = fmaf(fu[n][i], wr[i], a);
        fused[n][o] = a * em[n];
    }
    __syncthreads();

    for (int d = t; d < 3072; d += 256) {
        int n = d / 192, rr = d - n * 192;
        float a = in_b[rr];
        const float* wr = in_w + rr * 64;
        #pragma unroll
        for (int i = 0; i < 64; ++i) a = fmaf(fused[n][i], wr[i], a);
        qkvs[n][rr] = a;
    }
    __syncthreads();

    for (int d = t; d < 1024; d += 256) {
        int h = d >> 8, i = (d >> 4) & 15, j = d & 15;
        float a = 0.0f;
        #pragma unroll
        for (int dd = 0; dd < 16; ++dd)
            a = fmaf(qkvs[i][h * 16 + dd], qkvs[j][64 + h * 16 + dd], a);
        a *= 0.25f;
        if (em[j] < 0.5f) a = -1e30f;
        sc[h][i][j] = a;
    }
    __syncthreads();

    if (t < 64) {
        int h = t >> 4, i = t & 15;
        float mx = -3.4e38f;
        #pragma unroll
        for (int j = 0; j < 16; ++j) mx = fmaxf(mx, sc[h][i][j]);
        float e[16];
        float s = 0.0f;
        #pragma unroll
        for (int j = 0; j < 16; ++j) { e[j] = expf(sc[h][i][j] - mx); s += e[j]; }
        float inv = 1.0f / s;
        #pragma unroll
        for (int j = 0; j < 16; ++j) sc[h][i][j] = e[j] * inv;
    }
    __syncthreads();

    for (int d = t; d < 1024; d += 256) {
        int n = d >> 6, e = d & 63, h = e >> 4;
        float a = 0.0f;
        #pragma unroll
        for (int j = 0; j < 16; ++j)
            a = fmaf(sc[h][n][j], qkvs[j][128 + e], a);
        ao[n][e] = a;
    }
    __syncthreads();

    for (int d = t; d < 1024; d += 256) {
        int n = d >> 6, o = d & 63;
        float a = out_b[o];
        const float* wr = out_w + o * 64;
        #pragma unroll
        for (int i = 0; i < 64; ++i) a = fmaf(ao[n][i], wr[i], a);
        aoo[n][o] = a * em[n];
    }
    __syncthreads();

    if (t < 64) {
        float s = 0.0f, ms = 0.0f;
        #pragma unroll
        for (int n = 0; n < 16; ++n) { s += aoo[n][t]; ms += em[n]; }
        p2s[t] = s / (ms + 1e-8f);
    }
    __syncthreads();

    if (t < 64) {
        float a = b_fc1[t];
        const float* wr = w_fc1 + t * 64;
        #pragma unroll
        for (int i = 0; i < 64; ++i) a = fmaf(p2s[i], wr[i], a);
        hs[t] = fmaxf(a, 0.0f);
    }
    __syncthreads();

    if (t < 64) {
        float v = hs[t] * w_fc2[t];
        #pragma unroll
        for (int d2 = 32; d2 >= 1; d2 >>= 1) v += __shfl_xor(v, d2);
        if (t == 0) out[b] = v + b_fc2[0];
    }
}

extern "C" void kernel_launch(void* const* d_in, const int* in_sizes, int n_in,
                              void* d_out, int out_size, void* d_ws, size_t ws_size,
                              hipStream_t stream)
{
    (void)in_sizes; (void)n_in; (void)out_size; (void)ws_size;
    const float* x     = (const float*)d_in[0];
    const float* xmask = (const float*)d_in[1];
    const float* einfo = (const float*)d_in[2];
    const float* emask = (const float*)d_in[3];

    float* xfeatP = (float*)d_ws;                 // 3*512*32 f32 = 196.6 KB
    short* wp3 = (short*)(xfeatP + 3 * 512 * 32); // 3072*8 shorts
    short* wp5 = wp3 + 24576;                     // 5120*8 shorts
    short* wp7 = wp5 + 40960;                     // 7168*8 shorts

    pack_kernel<<<60, 256, 0, stream>>>(
        (const float*)d_in[6], (const float*)d_in[10], (const float*)d_in[14],
        wp3, wp5, wp7);

    branch_fused<<<1536, 256, 0, stream>>>(x, xmask,
        (const float*)d_in[4],  (const float*)d_in[5],  (const float*)d_in[7],  wp3,
        (const float*)d_in[8],  (const float*)d_in[9],  (const float*)d_in[11], wp5,
        (const float*)d_in[12], (const float*)d_in[13], (const float*)d_in[15], wp7,
        (const float*)d_in[16], xfeatP);

    tail_kernel<<<32, 256, 0, stream>>>(xfeatP,
        (const float*)d_in[17], xmask, einfo, emask,
        (const float*)d_in[18], (const float*)d_in[19],
        (const float*)d_in[20], (const float*)d_in[21],
        (const float*)d_in[22], (const float*)d_in[23],
        (const float*)d_in[24], (const float*)d_in[25],
        (const float*)d_in[26], (const float*)d_in[27],
        (const float*)d_in[28], (const float*)d_in[29],
        (const float*)d_in[30], (const float*)d_in[31],
        (float*)d_out);
}

// Round 14
// 70.191 us; speedup vs baseline: 1.6742x; 1.0214x over previous
//
#include <hip/hip_runtime.h>
#include <math.h>

typedef float f32x4 __attribute__((ext_vector_type(4)));
typedef short short8 __attribute__((ext_vector_type(8)));

__device__ __forceinline__ short bf16r(float f) {
    union { float f; unsigned u; } x; x.f = f;
    unsigned u = x.u + 0x7fffu + ((x.u >> 16) & 1u);
    return (short)(u >> 16);
}

// ---------------------------------------------------------------------------
// pack_kernel (16x16x32 format, verified r1-r13)
// ---------------------------------------------------------------------------
template<int K>
__device__ __forceinline__ void pack_branch(const float* __restrict__ w2,
                                            short* __restrict__ wpack, int u) {
    int lane = u & 63;
    int kb   = (u >> 6) & 1;
    int rem  = u >> 7;          // c*K + j
    int j = rem % K, c = rem / K;
    int co  = c * 16 + (lane & 15);
    int cib = kb * 32 + 8 * ((lane >> 4) & 3);
    short8 v;
    #pragma unroll
    for (int i = 0; i < 8; ++i)
        v[i] = bf16r(w2[(co * 64 + (cib + i)) * K + j]);
    *reinterpret_cast<short8*>(wpack + (size_t)u * 8) = v;
}

__global__ __launch_bounds__(256) void pack_kernel(
    const float* __restrict__ w23, const float* __restrict__ w25,
    const float* __restrict__ w27,
    short* __restrict__ wp3, short* __restrict__ wp5, short* __restrict__ wp7)
{
    int tid = blockIdx.x * 256 + threadIdx.x;
    const int n3 = 8 * 3 * 2 * 64;   // 3072
    const int n5 = 8 * 5 * 2 * 64;   // 5120
    const int n7 = 8 * 7 * 2 * 64;   // 7168
    if (tid < n3)                pack_branch<3>(w23, wp3, tid);
    else if (tid < n3 + n5)      pack_branch<5>(w25, wp5, tid - n3);
    else if (tid < n3 + n5 + n7) pack_branch<7>(w27, wp7, tid - n3 - n5);
}

// ---------------------------------------------------------------------------
// mfma_pass2<K,LT0,NLT>: dual-c lt-pass, rolled m-loop + named 1-deep B
// prefetch (spill-safe, r13-verified). One A-read feeds 2 MFMAs.
// ---------------------------------------------------------------------------
template<int K, int LT0, int NLT>
__device__ __forceinline__ void mfma_pass2(
    const short* __restrict__ t1s,
    const short8* __restrict__ wpB0, const short8* __restrict__ wpB1,
    int lane, f32x4* accA, f32x4* accB)
{
    constexpr int PAD = (K - 1) / 2;
    const int lane15 = lane & 15;
    const int g8 = 8 * ((lane >> 4) & 3);
    short8 bA = wpB0[0], bB = wpB1[0];
    #pragma unroll 1
    for (int m = 0; m < 2 * K - 1; ++m) {
        const short8 nA = wpB0[(m + 1) * 64];
        const short8 nB = wpB1[(m + 1) * 64];
        const int j = m >> 1, kb = m & 1;
        const int r = LT0 * 16 + lane15 + 3 + j - PAD;
        const int col = (kb * 32 + g8) ^ ((r & 7) << 3);
        const short* ab = &t1s[r * 64 + col];
        #pragma unroll
        for (int lt = 0; lt < NLT; ++lt) {
            const short8 af = *reinterpret_cast<const short8*>(ab + lt * 1024);
            accA[lt] = __builtin_amdgcn_mfma_f32_16x16x32_bf16(af, bA, accA[lt], 0, 0, 0);
            accB[lt] = __builtin_amdgcn_mfma_f32_16x16x32_bf16(af, bB, accB[lt], 0, 0, 0);
        }
        bA = nA; bB = nB;
    }
    {   // peeled last group
        const int m = 2 * K - 1;
        const int j = m >> 1, kb = m & 1;
        const int r = LT0 * 16 + lane15 + 3 + j - PAD;
        const int col = (kb * 32 + g8) ^ ((r & 7) << 3);
        const short* ab = &t1s[r * 64 + col];
        #pragma unroll
        for (int lt = 0; lt < NLT; ++lt) {
            const short8 af = *reinterpret_cast<const short8*>(ab + lt * 1024);
            accA[lt] = __builtin_amdgcn_mfma_f32_16x16x32_bf16(af, bA, accA[lt], 0, 0, 0);
            accB[lt] = __builtin_amdgcn_mfma_f32_16x16x32_bf16(af, bB, accB[lt], 0, 0, 0);
        }
    }
}

// pool_accum<GV,LT0,NLT>: C/D col=lane&15, row=4g+r4 (verified r1-r13).
template<int GV, int LT0, int NLT>
__device__ __forceinline__ void pool_accum(const f32x4* acc, float bb, float* pb) {
    #pragma unroll
    for (int lt = 0; lt < NLT; ++lt) {
        #pragma unroll
        for (int r4 = 0; r4 < 4; ++r4) {
            const int l = (LT0 + lt) * 16 + 4 * GV + r4;   // compile-time
            if (l < 200)
                pb[l / 20] += fmaxf(acc[lt][r4] + bb, 0.0f);
        }
    }
}

template<int K, int LT0, int NLT>
__device__ __forceinline__ void do_pass2(
    const short* __restrict__ t1s,
    const short8* __restrict__ wpB0, const short8* __restrict__ wpB1,
    int lane, float bb0, float bb1, float* pb0, float* pb1)
{
    const int g = (lane >> 4) & 3;
    f32x4 accA[NLT], accB[NLT];
    #pragma unroll
    for (int i = 0; i < NLT; ++i) {
        f32x4 z = {0.f, 0.f, 0.f, 0.f};
        accA[i] = z; accB[i] = z;
    }
    mfma_pass2<K, LT0, NLT>(t1s, wpB0, wpB1, lane, accA, accB);
    if      (g == 0) { pool_accum<0, LT0, NLT>(accA, bb0, pb0); pool_accum<0, LT0, NLT>(accB, bb1, pb1); }
    else if (g == 1) { pool_accum<1, LT0, NLT>(accA, bb0, pb0); pool_accum<1, LT0, NLT>(accB, bb1, pb1); }
    else if (g == 2) { pool_accum<2, LT0, NLT>(accA, bb0, pb0); pool_accum<2, LT0, NLT>(accB, bb1, pb1); }
    else             { pool_accum<3, LT0, NLT>(accA, bb0, pb0); pool_accum<3, LT0, NLT>(accB, bb1, pb1); }
}

// ---------------------------------------------------------------------------
// branch_body<K>: unchanged from r13 (verified clean + fastest so far).
// ---------------------------------------------------------------------------
template<int K>
__device__ __forceinline__ void branch_body(
    const int bn, const int t,
    const float* __restrict__ x,
    const float* __restrict__ w1, const float* __restrict__ b1,
    const float* __restrict__ b2, const short* __restrict__ wpack,
    const float* __restrict__ w_xfc_br, float* __restrict__ xfeatP_br,
    float* xs, short* t1s, float* pooled_s, float* b2s)
{
    constexpr int PAD = (K - 1) / 2;
    const int lane = t & 63;
    const int w    = t >> 6;            // 0..3, owns c = 2w, 2w+1
    const int lane15 = lane & 15;

    if (t < 208) xs[t] = 0.0f;
    for (int idx = t; idx < 32 * 64; idx += 256) {  // halo rows 0..2, 203..231
        int rr = idx >> 6;
        int row = (rr < 3) ? rr : (200 + rr);
        t1s[row * 64 + (idx & 63)] = 0;
    }
    if (t < 128) b2s[t] = b2[t];
    __syncthreads();

    if (t < 200) xs[3 + t] = x[bn * 200 + t];
    __syncthreads();

    // conv1, register-window (wave-uniform broadcast reads)
    {
        float w1_0 = w1[lane * K + 0], w1_1 = w1[lane * K + 1], w1_2 = w1[lane * K + 2];
        float w1_3 = 0.f, w1_4 = 0.f, w1_5 = 0.f, w1_6 = 0.f;
        if (K > 3) { w1_3 = w1[lane * K + 3]; w1_4 = w1[lane * K + 4]; }
        if (K > 5) { w1_5 = w1[lane * K + 5]; w1_6 = w1[lane * K + 6]; }
        const float b1r = b1[lane];
        #pragma unroll 1
        for (int ch = 0; ch < 2; ++ch) {
            const int lb = 50 * w + 25 * ch;       // wave-uniform base
            float xr[31];
            #pragma unroll
            for (int i = 0; i < 31; ++i) xr[i] = xs[lb + i];   // broadcast reads
            #pragma unroll
            for (int ll = 0; ll < 25; ++ll) {
                float a = b1r;
                a = fmaf(w1_0, xr[ll + 3 - PAD + 0], a);
                a = fmaf(w1_1, xr[ll + 3 - PAD + 1], a);
                a = fmaf(w1_2, xr[ll + 3 - PAD + 2], a);
                if (K > 3) {
                    a = fmaf(w1_3, xr[ll + 3 - PAD + 3], a);
                    a = fmaf(w1_4, xr[ll + 3 - PAD + 4], a);
                }
                if (K > 5) {
                    a = fmaf(w1_5, xr[ll + 3 - PAD + 5], a);
                    a = fmaf(w1_6, xr[ll + 3 - PAD + 6], a);
                }
                const int row = lb + ll + 3;
                t1s[row * 64 + (lane ^ ((row & 7) << 3))] = bf16r(fmaxf(a, 0.0f));
            }
        }
    }
    __syncthreads();

    const int c0 = 2 * w, c1 = 2 * w + 1;
    const int coA = c0 * 16 + lane15, coB = c1 * 16 + lane15;
    const float bb0 = b2s[coA], bb1 = b2s[coB];
    const short8* wpB0 = reinterpret_cast<const short8*>(wpack)
                         + (size_t)(c0 * 2 * K) * 64 + lane;
    const short8* wpB1 = reinterpret_cast<const short8*>(wpack)
                         + (size_t)(c1 * 2 * K) * 64 + lane;

    float pb0[10], pb1[10];
    #pragma unroll
    for (int b = 0; b < 10; ++b) { pb0[b] = 0.0f; pb1[b] = 0.0f; }

    do_pass2<K, 0, 7>(t1s, wpB0, wpB1, lane, bb0, bb1, pb0, pb1);
    do_pass2<K, 7, 6>(t1s, wpB0, wpB1, lane, bb0, bb1, pb0, pb1);

    #pragma unroll
    for (int b = 0; b < 10; ++b) {
        pb0[b] += __shfl_xor(pb0[b], 16);
        pb0[b] += __shfl_xor(pb0[b], 32);
        pb1[b] += __shfl_xor(pb1[b], 16);
        pb1[b] += __shfl_xor(pb1[b], 32);
    }
    if (lane < 16) {
        #pragma unroll
        for (int b = 0; b < 10; ++b) {
            pooled_s[coA * 10 + b] = pb0[b];
            pooled_s[coB * 10 + b] = pb1[b];
        }
    }
    __syncthreads();

    // xfc partial: o = t>>3 (0..31), part = t&7; coalesced f32x4
    {
        const int o = t >> 3, part = t & 7;
        const f32x4* wr4 = reinterpret_cast<const f32x4*>(w_xfc_br + o * 3840);
        const f32x4* pp4 = reinterpret_cast<const f32x4*>(pooled_s);
        float s0 = 0.0f, s1 = 0.0f;
        #pragma unroll
        for (int i = 0; i < 40; ++i) {
            const f32x4 wv = wr4[part + 8 * i];
            const f32x4 pv = pp4[part + 8 * i];
            float s = wv[0] * pv[0];
            s = fmaf(wv[1], pv[1], s);
            s = fmaf(wv[2], pv[2], s);
            s = fmaf(wv[3], pv[3], s);
            if (i & 1) s1 += s; else s0 += s;
        }
        float a = s0 + s1;
        a += __shfl_xor(a, 1);
        a += __shfl_xor(a, 2);
        a += __shfl_xor(a, 4);
        if (part == 0) xfeatP_br[bn * 32 + o] = a * 0.05f;
    }
}

__global__ __launch_bounds__(256, 4) void branch_fused(
    const float* __restrict__ x, const float* __restrict__ xmask,
    const float* __restrict__ w1_3, const float* __restrict__ b1_3,
    const float* __restrict__ b2_3, const short* __restrict__ wp3,
    const float* __restrict__ w1_5, const float* __restrict__ b1_5,
    const float* __restrict__ b2_5, const short* __restrict__ wp5,
    const float* __restrict__ w1_7, const float* __restrict__ b1_7,
    const float* __restrict__ b2_7, const short* __restrict__ wp7,
    const float* __restrict__ w_xfc, float* __restrict__ xfeatP)
{
    __shared__ float xs[208];
    __shared__ short t1s[232 * 64];
    __shared__ __align__(16) float pooled_s[1280];
    __shared__ float b2s[128];

    const int bx = blockIdx.x;
    const int br = bx % 3;          // interleave K=3/5/7 in every generation
    const int bn = bx / 3;
    const int t  = threadIdx.x;

    if (xmask[bn] == 0.0f) return;  // tail multiplies row by 0 -> exact

    if (br == 0)
        branch_body<3>(bn, t, x, w1_3, b1_3, b2_3, wp3,
                       w_xfc,        xfeatP,             xs, t1s, pooled_s, b2s);
    else if (br == 1)
        branch_body<5>(bn, t, x, w1_5, b1_5, b2_5, wp5,
                       w_xfc + 1280, xfeatP + 512 * 32,  xs, t1s, pooled_s, b2s);
    else
        branch_body<7>(bn, t, x, w1_7, b1_7, b2_7, wp7,
                       w_xfc + 2560, xfeatP + 1024 * 32, xs, t1s, pooled_s, b2s);
}

// ---------------------------------------------------------------------------
// Tail (rewritten for latency): all weight-row reads are f32x4; qkvs padded
// to [16][196] (784B rows: 16B-aligned, 2-way banks max); launch_bounds
// (256,1) frees the register budget so load batches are deep; one barrier
// removed (xfeat-load and element phases write disjoint fu columns).
// ---------------------------------------------------------------------------
__global__ __launch_bounds__(256, 1) void tail_kernel(
    const float* __restrict__ xfeatP,     // (3, 512, 32)
    const float* __restrict__ b_xfc,      // (32,)
    const float* __restrict__ xmaskp,     // (512,)
    const float* __restrict__ elem_info,  // (32, 16, 7)
    const float* __restrict__ emaskp,     // (32, 16)
    const float* __restrict__ w_float, const float* __restrict__ b_float,
    const float* __restrict__ atom_emb, const float* __restrict__ type_emb,
    const float* __restrict__ w_fuse,  const float* __restrict__ b_fuse,
    const float* __restrict__ in_w,    const float* __restrict__ in_b,
    const float* __restrict__ out_w,   const float* __restrict__ out_b,
    const float* __restrict__ w_fc1,   const float* __restrict__ b_fc1,
    const float* __restrict__ w_fc2,   const float* __restrict__ b_fc2,
    float* __restrict__ out)              // (32,)
{
    const int b = blockIdx.x;
    const int t = threadIdx.x;

    __shared__ __align__(16) float fu[16][60];     // 240B rows, aligned
    __shared__ __align__(16) float fused[16][64];
    __shared__ __align__(16) float qkvs[16][196];  // padded: 784B = 49*16
    __shared__ __align__(16) float sc[4][16][16];
    __shared__ __align__(16) float ao[16][64];
    __shared__ __align__(16) float aoo[16][64];
    __shared__ float p2s[64];
    __shared__ float hs[64];
    __shared__ float em[16];

    if (t < 16) em[t] = emaskp[b * 16 + t];

    // ---- merged phase: fu[:, :32] from xfeatP, fu[:, 32:60] from elements ----
    for (int d = t; d < 512; d += 256) {
        int n = d >> 5, o = d & 31;
        const int bn = b * 16 + n;
        float a = xfeatP[bn * 32 + o]
                + xfeatP[(512 + bn) * 32 + o]
                + xfeatP[(1024 + bn) * 32 + o];
        fu[n][o] = (a + b_xfc[o]) * xmaskp[bn];
    }
    {
        int n = t >> 4, slot = t & 15;
        float m  = emaskp[b * 16 + n];            // direct global (em not ready)
        float vE = (m >= 0.5f) ? 1.0f : 0.0f;
        const float* ei = elem_info + (b * 16 + n) * 7;
        float a = b_float[slot];
        #pragma unroll
        for (int i = 0; i < 5; ++i)
            a = fmaf(ei[i] * m, w_float[slot * 5 + i], a);
        fu[n][32 + slot] = fmaxf(a, 0.0f) * vE * m;

        int an = (int)(ei[5] * m);
        int et = (int)(ei[6] * m);
        float take = (vE != 0.0f && an >= 1 && an <= 94) ? 1.0f : 0.0f;
        int anc = an < 0 ? 0 : (an > 94 ? 94 : an);
        int etc = et < 0 ? 0 : (et > 5 ? 5 : et);
        if (slot < 8)
            fu[n][48 + slot] = atom_emb[anc * 8 + slot] * take * m;
        else if (slot < 12)
            fu[n][56 + (slot - 8)] = type_emb[etc * 4 + (slot - 8)] * take * m;
    }
    __syncthreads();

    // ---- fuse: f32x4 rows (60 = 15 x4) ----
    for (int d = t; d < 1024; d += 256) {
        int n = d >> 6, o = d & 63;
        const f32x4* wr4 = reinterpret_cast<const f32x4*>(w_fuse + o * 60);
        const f32x4* fr4 = reinterpret_cast<const f32x4*>(&fu[n][0]);
        float a0 = b_fuse[o], a1 = 0.0f;
        #pragma unroll
        for (int i = 0; i < 15; ++i) {
            const f32x4 wv = wr4[i];
            const f32x4 fv = fr4[i];
            float s = wv[0] * fv[0];
            s = fmaf(wv[1], fv[1], s);
            s = fmaf(wv[2], fv[2], s);
            s = fmaf(wv[3], fv[3], s);
            if (i & 1) a1 += s; else a0 += s;
        }
        fused[n][o] = (a0 + a1) * em[n];
    }
    __syncthreads();

    // ---- qkv: f32x4 rows (64 = 16 x4), padded dest ----
    for (int d = t; d < 3072; d += 256) {
        int n = d / 192, rr = d - n * 192;
        const f32x4* wr4 = reinterpret_cast<const f32x4*>(in_w + rr * 64);
        const f32x4* fr4 = reinterpret_cast<const f32x4*>(&fused[n][0]);
        float a0 = in_b[rr], a1 = 0.0f;
        #pragma unroll
        for (int i = 0; i < 16; ++i) {
            const f32x4 wv = wr4[i];
            const f32x4 fv = fr4[i];
            float s = wv[0] * fv[0];
            s = fmaf(wv[1], fv[1], s);
            s = fmaf(wv[2], fv[2], s);
            s = fmaf(wv[3], fv[3], s);
            if (i & 1) a1 += s; else a0 += s;
        }
        qkvs[n][rr] = a0 + a1;
    }
    __syncthreads();

    // ---- scores: f32x4 over dh=16 ----
    for (int d = t; d < 1024; d += 256) {
        int h = d >> 8, i = (d >> 4) & 15, j = d & 15;
        const f32x4* qi = reinterpret_cast<const f32x4*>(&qkvs[i][h * 16]);
        const f32x4* kj = reinterpret_cast<const f32x4*>(&qkvs[j][64 + h * 16]);
        float a = 0.0f;
        #pragma unroll
        for (int q4 = 0; q4 < 4; ++q4) {
            const f32x4 qv = qi[q4];
            const f32x4 kv = kj[q4];
            a = fmaf(qv[0], kv[0], a);
            a = fmaf(qv[1], kv[1], a);
            a = fmaf(qv[2], kv[2], a);
            a = fmaf(qv[3], kv[3], a);
        }
        a *= 0.25f;                                 // 1/sqrt(16)
        if (em[j] < 0.5f) a = -1e30f;
        sc[h][i][j] = a;
    }
    __syncthreads();

    if (t < 64) {
        int h = t >> 4, i = t & 15;
        float mx = -3.4e38f;
        #pragma unroll
        for (int j = 0; j < 16; ++j) mx = fmaxf(mx, sc[h][i][j]);
        float e[16];
        float s = 0.0f;
        #pragma unroll
        for (int j = 0; j < 16; ++j) { e[j] = expf(sc[h][i][j] - mx); s += e[j]; }
        float inv = 1.0f / s;
        #pragma unroll
        for (int j = 0; j < 16; ++j) sc[h][i][j] = e[j] * inv;
    }
    __syncthreads();

    // ---- attn @ V ----
    for (int d = t; d < 1024; d += 256) {
        int n = d >> 6, e = d & 63, h = e >> 4;
        float a = 0.0f;
        #pragma unroll
        for (int j = 0; j < 16; ++j)
            a = fmaf(sc[h][n][j], qkvs[j][128 + e], a);
        ao[n][e] = a;
    }
    __syncthreads();

    // ---- output projection: f32x4 rows ----
    for (int d = t; d < 1024; d += 256) {
        int n = d >> 6, o = d & 63;
        const f32x4* wr4 = reinterpret_cast<const f32x4*>(out_w + o * 64);
        const f32x4* ar4 = reinterpret_cast<const f32x4*>(&ao[n][0]);
        float a0 = out_b[o], a1 = 0.0f;
        #pragma unroll
        for (int i = 0; i < 16; ++i) {
            const f32x4 wv = wr4[i];
            const f32x4 av = ar4[i];
            float s = wv[0] * av[0];
            s = fmaf(wv[1], av[1], s);
            s = fmaf(wv[2], av[2], s);
            s = fmaf(wv[3], av[3], s);
            if (i & 1) a1 += s; else a0 += s;
        }
        aoo[n][o] = (a0 + a1) * em[n];
    }
    __syncthreads();

    if (t < 64) {
        float s = 0.0f, ms = 0.0f;
        #pragma unroll
        for (int n = 0; n < 16; ++n) { s += aoo[n][t]; ms += em[n]; }
        p2s[t] = s / (ms + 1e-8f);
    }
    __syncthreads();

    // ---- fc1 + relu: f32x4 rows ----
    if (t < 64) {
        const f32x4* wr4 = reinterpret_cast<const f32x4*>(w_fc1 + t * 64);
        const f32x4* pr4 = reinterpret_cast<const f32x4*>(p2s);
        float a0 = b_fc1[t], a1 = 0.0f;
        #pragma unroll
        for (int i = 0; i < 16; ++i) {
            const f32x4 wv = wr4[i];
            const f32x4 pv = pr4[i];
            float s = wv[0] * pv[0];
            s = fmaf(wv[1], pv[1], s);
            s = fmaf(wv[2], pv[2], s);
            s = fmaf(wv[3], pv[3], s);
            if (i & 1) a1 += s; else a0 += s;
        }
        hs[t] = fmaxf(a0 + a1, 0.0f);
    }
    __syncthreads();

    if (t < 64) {
        float v = hs[t] * w_fc2[t];
        #pragma unroll
        for (int d2 = 32; d2 >= 1; d2 >>= 1) v += __shfl_xor(v, d2);
        if (t == 0) out[b] = v + b_fc2[0];
    }
}

extern "C" void kernel_launch(void* const* d_in, const int* in_sizes, int n_in,
                              void* d_out, int out_size, void* d_ws, size_t ws_size,
                              hipStream_t stream)
{
    (void)in_sizes; (void)n_in; (void)out_size; (void)ws_size;
    const float* x     = (const float*)d_in[0];
    const float* xmask = (const float*)d_in[1];
    const float* einfo = (const float*)d_in[2];
    const float* emask = (const float*)d_in[3];

    float* xfeatP = (float*)d_ws;                 // 3*512*32 f32 = 196.6 KB
    short* wp3 = (short*)(xfeatP + 3 * 512 * 32); // 3072*8 shorts
    short* wp5 = wp3 + 24576;                     // 5120*8 shorts
    short* wp7 = wp5 + 40960;                     // 7168*8 shorts

    pack_kernel<<<60, 256, 0, stream>>>(
        (const float*)d_in[6], (const float*)d_in[10], (const float*)d_in[14],
        wp3, wp5, wp7);

    branch_fused<<<1536, 256, 0, stream>>>(x, xmask,
        (const float*)d_in[4],  (const float*)d_in[5],  (const float*)d_in[7],  wp3,
        (const float*)d_in[8],  (const float*)d_in[9],  (const float*)d_in[11], wp5,
        (const float*)d_in[12], (const float*)d_in[13], (const float*)d_in[15], wp7,
        (const float*)d_in[16], xfeatP);

    tail_kernel<<<32, 256, 0, stream>>>(xfeatP,
        (const float*)d_in[17], xmask, einfo, emask,
        (const float*)d_in[18], (const float*)d_in[19],
        (const float*)d_in[20], (const float*)d_in[21],
        (const float*)d_in[22], (const float*)d_in[23],
        (const float*)d_in[24], (const float*)d_in[25],
        (const float*)d_in[26], (const float*)d_in[27],
        (const float*)d_in[28], (const float*)d_in[29],
        (const float*)d_in[30], (const float*)d_in[31],
        (float*)d_out);
}